// Round 12
// baseline (493.751 us; speedup 1.0000x reference)
//
#include <hip/hip_runtime.h>
#include <cstdint>
#include <cstddef>

constexpr int kC = 1024;   // DIM
constexpr int kH = 16;     // heads
constexpr int kB = 4;      // batch
constexpr int kN = 2048;   // seq
constexpr int kD = 64;     // head dim

// softmax scale folded into Q at the QKV-GEMM epilogue: 0.125 * log2(e)
#define KQ_SCALE 0.18033688011112042f

typedef unsigned short u16;
typedef unsigned int   u32;
typedef unsigned long long u64;
typedef __bf16 v8bf  __attribute__((ext_vector_type(8)));
typedef float  v4f   __attribute__((ext_vector_type(4)));
typedef u16    u16x8 __attribute__((ext_vector_type(8)));
typedef u16    u16x4 __attribute__((ext_vector_type(4)));

__device__ inline u16 f2bf(float f) {
    union { float f; unsigned u; } v; v.f = f;
    unsigned r = v.u + 0x7FFFu + ((v.u >> 16) & 1u);   // RNE
    return (u16)(r >> 16);
}

__device__ inline float fast_exp2(float x) {
#if __has_builtin(__builtin_amdgcn_exp2f)
    return __builtin_amdgcn_exp2f(x);          // bare v_exp_f32
#else
    return __expf(x * 0.6931471805599453f);
#endif
}

// async 16B global -> LDS (wave-uniform LDS base + lane*16)
__device__ inline void gl2lds16(const u16* g, u16* l) {
    __builtin_amdgcn_global_load_lds(
        (const __attribute__((address_space(1))) void*)g,
        (__attribute__((address_space(3))) void*)l, 16, 0, 0);
}

// ---------------------------------------------------------------- casts
__global__ __launch_bounds__(256) void cast_bf16_kernel(
    const float* __restrict__ in, u16* __restrict__ outp)
{
    const int i = blockIdx.x * 256 + threadIdx.x;
    const float4 f = ((const float4*)in)[i];
    u16x4 o;
    o.x = f2bf(f.x); o.y = f2bf(f.y); o.z = f2bf(f.z); o.w = f2bf(f.w);
    ((u16x4*)outp)[i] = o;
}

// W [R][Cc] fp32 -> Wt [Cc][R] bf16, 64x64 LDS tiles
__global__ __launch_bounds__(256) void tpose_cast_kernel(
    const float* __restrict__ W, u16* __restrict__ Wt, int R, int Cc)
{
    __shared__ u16 tile[64][65];
    const int c0 = blockIdx.x * 64;
    const int r0 = blockIdx.y * 64;
    const int t  = threadIdx.x;
#pragma unroll
    for (int it = 0; it < 16; ++it) {
        const int r = it * 4 + (t >> 6);
        const int c = t & 63;
        tile[c][r] = f2bf(W[(size_t)(r0 + r) * Cc + c0 + c]);
    }
    __syncthreads();
#pragma unroll
    for (int it = 0; it < 16; ++it) {
        const int rr = it * 4 + (t >> 6);
        const int cc = t & 63;
        Wt[(size_t)(c0 + rr) * R + r0 + cc] = tile[rr][cc];
    }
}

// ------------------------------------------------------------ mask pack
// Grid-strided: 2048 blocks. Row-bitmap: row (b*N+q) is 2048 bits
// (64 u32), bit k set iff masked. (R5-proven version.)
__global__ __launch_bounds__(256) void maskpack_kernel(
    const int* __restrict__ mask, u32* __restrict__ bits)
{
    const int lane = threadIdx.x & 63;
    const int wv   = threadIdx.x >> 6;
    const int nseg = kB * kN * 32;
    for (int seg = blockIdx.x * 4 + wv; seg < nseg; seg += gridDim.x * 4) {
        const size_t row = (size_t)(seg >> 5);   // b*N + q
        const int s = seg & 31;                  // 64-key segment within row
        const int m = mask[row * kN + s * 64 + lane];
        const u64 bal = __ballot(m != 0);
        if (lane == 0) ((u64*)bits)[row * 32 + s] = bal;
    }
}

// ---------------------------------------------------- bf16 MFMA GEMM
// C[M,N] = A[M,K] @ Bt[N,K]^T + bias.  128x128 tile, BK=32, 4 waves.
// 3-buffer / 2-ahead pipeline with COUNTED vmcnt + raw s_barrier (T3/T4).
// R5/R10-proven config (best measured: non-attn ~227 us) — unchanged.
template <int MODE>
__global__ __launch_bounds__(256, 3) void gemm_mfma_kernel(
    const u16* __restrict__ A, const u16* __restrict__ Bt,
    const float* __restrict__ bias, float* __restrict__ Cout,
    u16* __restrict__ qOut, u16* __restrict__ kOut, u16* __restrict__ vOut,
    int M, int N, int K)
{
    __shared__ u16 As0[128 * 32], Bs0[128 * 32];
    __shared__ u16 As1[128 * 32], Bs1[128 * 32];
    __shared__ u16 As2[128 * 32], Bs2[128 * 32];
    const int t    = threadIdx.x;
    const int w    = t >> 6;
    const int lane = t & 63;
    const int quad = lane >> 4;
    const int l16  = lane & 15;

    // XCD-chunked bijective swizzle (nwg % 8 == 0), column-major walk
    const int nby = M >> 7;
    const int q8  = (int)gridDim.x >> 3;
    const int bid = (int)blockIdx.x;
    const int swz = (bid & 7) * q8 + (bid >> 3);
    const int m0  = (swz % nby) * 128;
    const int n0  = (swz / nby) * 128;

    const int sr  = lane >> 2;                              // staging row in 16
    const int scs = ((lane & 3) ^ ((sr >> 1) & 3)) * 8;     // swizzled src chunk
    const u16* Ag0 = A  + (size_t)(m0 + 32 * w      + sr) * K + scs;
    const u16* Ag1 = A  + (size_t)(m0 + 32 * w + 16 + sr) * K + scs;
    const u16* Bg0 = Bt + (size_t)(n0 + 32 * w      + sr) * K + scs;
    const u16* Bg1 = Bt + (size_t)(n0 + 32 * w + 16 + sr) * K + scs;

    v4f acc[4][4];
#pragma unroll
    for (int r = 0; r < 4; ++r)
#pragma unroll
        for (int c = 0; c < 4; ++c) acc[r][c] = (v4f){0.f, 0.f, 0.f, 0.f};

    const int mrow = (w >> 1) * 64;
    const int ncol = (w & 1) * 64;
    const int pch  = (quad ^ ((l16 >> 1) & 3)) * 8;         // swizzled read chunk

    auto stage = [&](u16* Asb, u16* Bsb, int k0) {
        gl2lds16(Ag0 + k0, Asb + (32 * w) * 32);
        gl2lds16(Ag1 + k0, Asb + (32 * w + 16) * 32);
        gl2lds16(Bg0 + k0, Bsb + (32 * w) * 32);
        gl2lds16(Bg1 + k0, Bsb + (32 * w + 16) * 32);
    };
    auto compute = [&](const u16* Asb, const u16* Bsb) {
        v8bf af[4], bfr[4];
#pragma unroll
        for (int r = 0; r < 4; ++r)
            af[r] = *(const v8bf*)(Asb + (mrow + r * 16 + l16) * 32 + pch);
#pragma unroll
        for (int c = 0; c < 4; ++c)
            bfr[c] = *(const v8bf*)(Bsb + (ncol + c * 16 + l16) * 32 + pch);
        __builtin_amdgcn_s_setprio(1);
#pragma unroll
        for (int r = 0; r < 4; ++r)
#pragma unroll
            for (int c = 0; c < 4; ++c)
                acc[r][c] = __builtin_amdgcn_mfma_f32_16x16x32_bf16(
                    af[r], bfr[c], acc[r][c], 0, 0, 0);
        __builtin_amdgcn_s_setprio(0);
    };

    // prologue: 2 tiles in flight
    stage(As0, Bs0, 0);
    stage(As1, Bs1, 32);
    u16 *pa0 = As0, *pb0 = Bs0, *pa1 = As1, *pb1 = Bs1, *pa2 = As2, *pb2 = Bs2;

    for (int k0 = 0; k0 < K; k0 += 32) {
        if (k0 + 32 < K) {
            // tile t's 4 loads retired (tile t+1's 4 may remain in flight)
            asm volatile("s_waitcnt vmcnt(4)" ::: "memory");
        } else {
            asm volatile("s_waitcnt vmcnt(0)" ::: "memory");
        }
        __builtin_amdgcn_s_barrier();
        __builtin_amdgcn_sched_barrier(0);
        if (k0 + 64 < K) stage(pa2, pb2, k0 + 64);
        compute(pa0, pb0);
        u16* ta = pa0; pa0 = pa1; pa1 = pa2; pa2 = ta;
        u16* tb = pb0; pb0 = pb1; pb1 = pb2; pb2 = tb;
    }

#pragma unroll
    for (int r = 0; r < 4; ++r) {
#pragma unroll
        for (int c = 0; c < 4; ++c) {
            const int col = n0 + ncol + c * 16 + l16;
            const float bv = bias[col];
#pragma unroll
            for (int reg = 0; reg < 4; ++reg) {
                const int row = m0 + mrow + r * 16 + quad * 4 + reg;
                float val = acc[r][c][reg] + bv;
                if (MODE == 0) {
                    Cout[(size_t)row * N + col] = val;
                } else {
                    const int which = col >> 10;
                    const int rem   = col & 1023;
                    const int h     = rem >> 6;
                    const int d     = rem & 63;
                    const int b     = row >> 11;
                    const int n     = row & 2047;
                    if (which == 0) val *= KQ_SCALE;   // fold softmax scale + log2e into Q
                    u16* dst = (which == 0) ? qOut : (which == 1) ? kOut : vOut;
                    dst[(((size_t)(b * kH + h)) * kN + n) * kD + d] = f2bf(val);
                }
            }
        }
    }
}

// ------------------------------------------------- MFMA attention (bf16)
// R8-proven body (128 q-rows/block, 4 waves x 32 rows as 2 strips, P in
// registers via permuted-k trick, ones-MFMA row-sums, pre-scaled Q).
// THIS ROUND: single-buffered LDS (32 KB, R3/R4-proven 2-barrier loop)
// + __launch_bounds__(256, 4) -> 4 blocks/CU (was 2 with 64 KB dbuf).
// Rationale: attn is flat 124-131 us across barrier structures at 2
// blocks/CU with MfmaUtil+VALUBusy ~78% — latency-bound on dependent
// softmax chains; doubling resident waves (8->16/CU) fills issue stalls.
// VGPR 92 fits the 128 cap; grid 1024 = exactly 4 blocks/CU.
// (R11's 64-row geometry REVERTED: VGPR cap forced scratch spills,
// WRITE_SIZE 16->83 MB, attn 154 us.)
__global__ __launch_bounds__(256, 4) void attn_mfma_kernel(
    const u16* __restrict__ q, const u16* __restrict__ k,
    const u16* __restrict__ v, const u32* __restrict__ mbits,
    u16* __restrict__ out)   // bf16 ao [B,N,C]
{
    __shared__ u16 Ks[128 * 64];   // 16 KB  [key][d], chunk ^= (key&7)
    __shared__ u16 Vt[64 * 128];   // 16 KB  [d][key-permuted], chunk ^= (d&15)

    const int t    = threadIdx.x;
    const int w    = t >> 6;
    const int lane = t & 63;
    const int quad = lane >> 4;
    const int l16  = lane & 15;

    const int bh    = blockIdx.x >> 4;          // 16 q-tiles of 128 rows
    const int tile0 = (blockIdx.x & 15) * 128;
    const int b     = bh >> 4;
    const int h     = bh & 15;

    const u16* qb = q + (size_t)bh * kN * kD;
    const u16* kb = k + (size_t)bh * kN * kD;
    const u16* vb = v + (size_t)bh * kN * kD;

    // Q B-fragments for 2 strips: lane holds Q[qrow][d = quad*8 + j]
    const int qrow0 = tile0 + w * 32 + l16;
    const int qrow1 = qrow0 + 16;
    v8bf qf[2][2];
    qf[0][0] = *(const v8bf*)(qb + (size_t)qrow0 * kD + quad * 8);
    qf[0][1] = *(const v8bf*)(qb + (size_t)qrow0 * kD + 32 + quad * 8);
    qf[1][0] = *(const v8bf*)(qb + (size_t)qrow1 * kD + quad * 8);
    qf[1][1] = *(const v8bf*)(qb + (size_t)qrow1 * kD + 32 + quad * 8);

    // staging geometry (constant per thread)
    // K: 2 rows x 32 dims per thread (4x 16B swizzled b128 writes)
    const int skr  = t >> 1;           // K row 0..127
    const int skh  = t & 1;            // K half (32 elems)
    // V: permuted 8 keys x 4 dims per thread -> 4x b128 transposed writes.
    const int vg   = t >> 4;           // frag chunk 0..15
    const int vdq  = t & 15;           // dim quad (dims vdq*4..+3)
    const int vrow0 = (vg >> 2) * 32 + (vg & 3) * 4;

    const u16* kp = kb + (size_t)skr * kD + skh * 32;
    const u16* vp = vb + (size_t)vrow0 * kD + vdq * 4;
    const uint4* mp0 = (const uint4*)(mbits + ((size_t)b * kN + qrow0) * 64);
    const uint4* mp1 = (const uint4*)(mbits + ((size_t)b * kN + qrow1) * 64);

    u16x8 kpre[4];
    u16x4 vpre[8];
    uint4 mpre0, mpre1;
    auto issue_prefetch = [&]() {
#pragma unroll
        for (int i = 0; i < 4; ++i)
            kpre[i] = *(const u16x8*)(kp + i * 8);
#pragma unroll
        for (int i = 0; i < 8; ++i)
            vpre[i] = *(const u16x4*)(vp + (i < 4 ? i * 64 : 1024 + (i - 4) * 64));
        mpre0 = *mp0; mpre1 = *mp1;
        kp += 128 * kD; vp += 128 * kD; ++mp0; ++mp1;
    };

    v8bf onesf;
#pragma unroll
    for (int j = 0; j < 8; ++j) onesf[j] = (__bf16)1.0f;

    v4f oacc[2][4];
    v4f rsacc[2];
#pragma unroll
    for (int qs = 0; qs < 2; ++qs) {
        rsacc[qs] = (v4f){0.f, 0.f, 0.f, 0.f};
#pragma unroll
        for (int i = 0; i < 4; ++i) oacc[qs][i] = (v4f){0.f, 0.f, 0.f, 0.f};
    }

    issue_prefetch();   // tile 0

    for (int kt = 0; kt < kN / 128; ++kt) {
        __syncthreads();   // prev tile's LDS reads done (WAR)

        // ---- stage tile kt from regs
        {
            const int cb = skh * 4;
            u16* drow = &Ks[skr * 64];
#pragma unroll
            for (int i = 0; i < 4; ++i)
                *(u16x8*)(&drow[((cb + i) ^ (skr & 7)) * 8]) = kpre[i];
        }
        {
#pragma unroll
            for (int dd = 0; dd < 4; ++dd) {
                const int d = vdq * 4 + dd;
                u16x8 col;
#pragma unroll
                for (int j = 0; j < 8; ++j) col[j] = vpre[j][dd];
                *(u16x8*)(&Vt[d * 128 + ((vg ^ (d & 15)) * 8)]) = col;
            }
        }
        const uint4 mc0 = mpre0, mc1 = mpre1;
        if (kt + 1 < kN / 128) issue_prefetch();   // regs free after ds_writes issue

        __syncthreads();   // staged tile visible

        const u32 mwa[2][4] = {{mc0.x, mc0.y, mc0.z, mc0.w},
                               {mc1.x, mc1.y, mc1.z, mc1.w}};
        v8bf pa[2][4];     // P A-fragments, built directly in registers

        // ---- S^T + softmax: lane gets s[reg] = S[key=nb*16+quad*4+reg][q=l16]
#pragma unroll
        for (int nb = 0; nb < 8; ++nb) {
            const int krow = nb * 16 + l16;
            const v8bf kf0 = *(const v8bf*)(&Ks[krow * 64 + ((quad       ^ (krow & 7)) * 8)]);
            const v8bf kf1 = *(const v8bf*)(&Ks[krow * 64 + (((quad + 4) ^ (krow & 7)) * 8)]);
#pragma unroll
            for (int qs = 0; qs < 2; ++qs) {
                v4f s = (v4f){0.f, 0.f, 0.f, 0.f};
                s = __builtin_amdgcn_mfma_f32_16x16x32_bf16(kf0, qf[qs][0], s, 0, 0, 0);
                s = __builtin_amdgcn_mfma_f32_16x16x32_bf16(kf1, qf[qs][1], s, 0, 0, 0);

                const u32 m4 = (mwa[qs][nb >> 1] >> ((nb & 1) * 16 + quad * 4)) & 0xFu;
                float e0 = fast_exp2(s[0]);
                float e1 = fast_exp2(s[1]);
                float e2 = fast_exp2(s[2]);
                float e3 = fast_exp2(s[3]);
                e0 = (m4 & 1u) ? 0.f : e0;
                e1 = (m4 & 2u) ? 0.f : e1;
                e2 = (m4 & 4u) ? 0.f : e2;
                e3 = (m4 & 8u) ? 0.f : e3;

                pa[qs][nb >> 1][(nb & 1) * 4 + 0] = (__bf16)e0;
                pa[qs][nb >> 1][(nb & 1) * 4 + 1] = (__bf16)e1;
                pa[qs][nb >> 1][(nb & 1) * 4 + 2] = (__bf16)e2;
                pa[qs][nb >> 1][(nb & 1) * 4 + 3] = (__bf16)e3;
            }
        }

        __builtin_amdgcn_s_setprio(1);
        // row-sums via ones-MFMA: rsacc row layout == oacc row layout
#pragma unroll
        for (int qs = 0; qs < 2; ++qs)
#pragma unroll
            for (int ks = 0; ks < 4; ++ks)
                rsacc[qs] = __builtin_amdgcn_mfma_f32_16x16x32_bf16(
                    pa[qs][ks], onesf, rsacc[qs], 0, 0, 0);
        // ---- PV: O[q][d] += P(32x128) @ V^T
#pragma unroll
        for (int ks = 0; ks < 4; ++ks)
#pragma unroll
            for (int db = 0; db < 4; ++db) {
                const int d = db * 16 + l16;
                const v8bf vf = *(const v8bf*)(&Vt[d * 128 + (((ks * 4 + quad) ^ (d & 15)) * 8)]);
#pragma unroll
                for (int qs = 0; qs < 2; ++qs)
                    oacc[qs][db] = __builtin_amdgcn_mfma_f32_16x16x32_bf16(
                        pa[qs][ks], vf, oacc[qs][db], 0, 0, 0);
            }
        __builtin_amdgcn_s_setprio(0);
    }

    // ---- normalize + store: rsacc rows already match oacc rows (quad*4+reg)
#pragma unroll
    for (int qs = 0; qs < 2; ++qs) {
        float inv[4];
#pragma unroll
        for (int reg = 0; reg < 4; ++reg) inv[reg] = 1.f / rsacc[qs][reg];
#pragma unroll
        for (int db = 0; db < 4; ++db)
#pragma unroll
            for (int reg = 0; reg < 4; ++reg) {
                const int row = tile0 + w * 32 + qs * 16 + quad * 4 + reg;
                const int col = h * 64 + db * 16 + l16;
                out[((size_t)(b * kN + row)) * kC + col] = f2bf(oacc[qs][db][reg] * inv[reg]);
            }
    }
}

// ------------------------------------------------------------------ launch
extern "C" void kernel_launch(void* const* d_in, const int* in_sizes, int n_in,
                              void* d_out, int out_size, void* d_ws, size_t ws_size,
                              hipStream_t stream)
{
    const float* x     = (const float*)d_in[0];
    const int*   mask  = (const int*)d_in[1];
    const float* Wqkv  = (const float*)d_in[2];
    const float* bqkv  = (const float*)d_in[3];
    const float* Wproj = (const float*)d_in[4];
    const float* bproj = (const float*)d_in[5];
    float* out = (float*)d_out;

    const size_t nx = (size_t)kB * kN * kC;
    const size_t qkv_elems = (size_t)kB * kH * kN * kD;
    u16* xb     = (u16*)d_ws;
    u16* qbuf   = xb + nx;
    u16* kbuf   = qbuf + qkv_elems;
    u16* vbuf   = kbuf + qkv_elems;
    u16* aob    = vbuf + qkv_elems;
    u16* Wqkvt  = aob + nx;
    u16* Wprojt = Wqkvt + (size_t)3 * kC * kC;
    u32* mbits  = (u32*)(Wprojt + (size_t)kC * kC);   // 2 MB bitmask

    maskpack_kernel<<<dim3(2048), dim3(256), 0, stream>>>(mask, mbits);
    cast_bf16_kernel<<<dim3(nx / 1024), dim3(256), 0, stream>>>(x, xb);
    tpose_cast_kernel<<<dim3(3 * kC / 64, kC / 64), dim3(256), 0, stream>>>(
        Wqkv, Wqkvt, kC, 3 * kC);
    tpose_cast_kernel<<<dim3(kC / 64, kC / 64), dim3(256), 0, stream>>>(
        Wproj, Wprojt, kC, kC);

    // 1-D grids (XCD swizzle inside): nwg = (N/128)*(M/128), % 8 == 0
    gemm_mfma_kernel<1><<<dim3((3 * kC / 128) * (kB * kN / 128)), dim3(256), 0, stream>>>(
        xb, Wqkvt, bqkv, nullptr, qbuf, kbuf, vbuf, kB * kN, 3 * kC, kC);

    attn_mfma_kernel<<<dim3(kB * kH * (kN / 128)), dim3(256), 0, stream>>>(
        qbuf, kbuf, vbuf, mbits, aob);

    gemm_mfma_kernel<0><<<dim3((kC / 128) * (kB * kN / 128)), dim3(256), 0, stream>>>(
        aob, Wprojt, bproj, out, nullptr, nullptr, nullptr, kB * kN, kC, kC);
}

// Round 13
// 370.392 us; speedup vs baseline: 1.3331x; 1.3331x over previous
//
#include <hip/hip_runtime.h>
#include <cstdint>
#include <cstddef>

constexpr int kC = 1024;   // DIM
constexpr int kH = 16;     // heads
constexpr int kB = 4;      // batch
constexpr int kN = 2048;   // seq
constexpr int kD = 64;     // head dim

// softmax scale folded into Q at the QKV-GEMM epilogue: 0.125 * log2(e)
#define KQ_SCALE 0.18033688011112042f

typedef unsigned short u16;
typedef unsigned int   u32;
typedef unsigned long long u64;
typedef __bf16 v8bf  __attribute__((ext_vector_type(8)));
typedef float  v4f   __attribute__((ext_vector_type(4)));
typedef u16    u16x8 __attribute__((ext_vector_type(8)));
typedef u16    u16x4 __attribute__((ext_vector_type(4)));

__device__ inline u16 f2bf(float f) {
    union { float f; unsigned u; } v; v.f = f;
    unsigned r = v.u + 0x7FFFu + ((v.u >> 16) & 1u);   // RNE
    return (u16)(r >> 16);
}

__device__ inline float fast_exp2(float x) {
#if __has_builtin(__builtin_amdgcn_exp2f)
    return __builtin_amdgcn_exp2f(x);          // bare v_exp_f32
#else
    return __expf(x * 0.6931471805599453f);
#endif
}

// async 16B global -> LDS (wave-uniform LDS base + lane*16)
__device__ inline void gl2lds16(const u16* g, u16* l) {
    __builtin_amdgcn_global_load_lds(
        (const __attribute__((address_space(1))) void*)g,
        (__attribute__((address_space(3))) void*)l, 16, 0, 0);
}

// ---------------------------------------------------------------- casts
__global__ __launch_bounds__(256) void cast_bf16_kernel(
    const float* __restrict__ in, u16* __restrict__ outp)
{
    const int i = blockIdx.x * 256 + threadIdx.x;
    const float4 f = ((const float4*)in)[i];
    u16x4 o;
    o.x = f2bf(f.x); o.y = f2bf(f.y); o.z = f2bf(f.z); o.w = f2bf(f.w);
    ((u16x4*)outp)[i] = o;
}

// W [R][Cc] fp32 -> Wt [Cc][R] bf16, 64x64 LDS tiles
__global__ __launch_bounds__(256) void tpose_cast_kernel(
    const float* __restrict__ W, u16* __restrict__ Wt, int R, int Cc)
{
    __shared__ u16 tile[64][65];
    const int c0 = blockIdx.x * 64;
    const int r0 = blockIdx.y * 64;
    const int t  = threadIdx.x;
#pragma unroll
    for (int it = 0; it < 16; ++it) {
        const int r = it * 4 + (t >> 6);
        const int c = t & 63;
        tile[c][r] = f2bf(W[(size_t)(r0 + r) * Cc + c0 + c]);
    }
    __syncthreads();
#pragma unroll
    for (int it = 0; it < 16; ++it) {
        const int rr = it * 4 + (t >> 6);
        const int cc = t & 63;
        Wt[(size_t)(c0 + rr) * R + r0 + cc] = tile[rr][cc];
    }
}

// ------------------------------------------------------------ mask pack
// Grid-strided: 2048 blocks. Row-bitmap: row (b*N+q) is 2048 bits
// (64 u32), bit k set iff masked. (R5-proven version.)
__global__ __launch_bounds__(256) void maskpack_kernel(
    const int* __restrict__ mask, u32* __restrict__ bits)
{
    const int lane = threadIdx.x & 63;
    const int wv   = threadIdx.x >> 6;
    const int nseg = kB * kN * 32;
    for (int seg = blockIdx.x * 4 + wv; seg < nseg; seg += gridDim.x * 4) {
        const size_t row = (size_t)(seg >> 5);   // b*N + q
        const int s = seg & 31;                  // 64-key segment within row
        const int m = mask[row * kN + s * 64 + lane];
        const u64 bal = __ballot(m != 0);
        if (lane == 0) ((u64*)bits)[row * 32 + s] = bal;
    }
}

// ---------------------------------------------------- bf16 MFMA GEMM
// C[M,N] = A[M,K] @ Bt[N,K]^T + bias.  128x128 tile, BK=32, 4 waves.
// 3-buffer / 2-ahead pipeline with COUNTED vmcnt + raw s_barrier (T3/T4).
// R5/R10-proven config (best measured: non-attn ~227 us) — unchanged.
template <int MODE>
__global__ __launch_bounds__(256, 3) void gemm_mfma_kernel(
    const u16* __restrict__ A, const u16* __restrict__ Bt,
    const float* __restrict__ bias, float* __restrict__ Cout,
    u16* __restrict__ qOut, u16* __restrict__ kOut, u16* __restrict__ vOut,
    int M, int N, int K)
{
    __shared__ u16 As0[128 * 32], Bs0[128 * 32];
    __shared__ u16 As1[128 * 32], Bs1[128 * 32];
    __shared__ u16 As2[128 * 32], Bs2[128 * 32];
    const int t    = threadIdx.x;
    const int w    = t >> 6;
    const int lane = t & 63;
    const int quad = lane >> 4;
    const int l16  = lane & 15;

    // XCD-chunked bijective swizzle (nwg % 8 == 0), column-major walk
    const int nby = M >> 7;
    const int q8  = (int)gridDim.x >> 3;
    const int bid = (int)blockIdx.x;
    const int swz = (bid & 7) * q8 + (bid >> 3);
    const int m0  = (swz % nby) * 128;
    const int n0  = (swz / nby) * 128;

    const int sr  = lane >> 2;                              // staging row in 16
    const int scs = ((lane & 3) ^ ((sr >> 1) & 3)) * 8;     // swizzled src chunk
    const u16* Ag0 = A  + (size_t)(m0 + 32 * w      + sr) * K + scs;
    const u16* Ag1 = A  + (size_t)(m0 + 32 * w + 16 + sr) * K + scs;
    const u16* Bg0 = Bt + (size_t)(n0 + 32 * w      + sr) * K + scs;
    const u16* Bg1 = Bt + (size_t)(n0 + 32 * w + 16 + sr) * K + scs;

    v4f acc[4][4];
#pragma unroll
    for (int r = 0; r < 4; ++r)
#pragma unroll
        for (int c = 0; c < 4; ++c) acc[r][c] = (v4f){0.f, 0.f, 0.f, 0.f};

    const int mrow = (w >> 1) * 64;
    const int ncol = (w & 1) * 64;
    const int pch  = (quad ^ ((l16 >> 1) & 3)) * 8;         // swizzled read chunk

    auto stage = [&](u16* Asb, u16* Bsb, int k0) {
        gl2lds16(Ag0 + k0, Asb + (32 * w) * 32);
        gl2lds16(Ag1 + k0, Asb + (32 * w + 16) * 32);
        gl2lds16(Bg0 + k0, Bsb + (32 * w) * 32);
        gl2lds16(Bg1 + k0, Bsb + (32 * w + 16) * 32);
    };
    auto compute = [&](const u16* Asb, const u16* Bsb) {
        v8bf af[4], bfr[4];
#pragma unroll
        for (int r = 0; r < 4; ++r)
            af[r] = *(const v8bf*)(Asb + (mrow + r * 16 + l16) * 32 + pch);
#pragma unroll
        for (int c = 0; c < 4; ++c)
            bfr[c] = *(const v8bf*)(Bsb + (ncol + c * 16 + l16) * 32 + pch);
        __builtin_amdgcn_s_setprio(1);
#pragma unroll
        for (int r = 0; r < 4; ++r)
#pragma unroll
            for (int c = 0; c < 4; ++c)
                acc[r][c] = __builtin_amdgcn_mfma_f32_16x16x32_bf16(
                    af[r], bfr[c], acc[r][c], 0, 0, 0);
        __builtin_amdgcn_s_setprio(0);
    };

    // prologue: 2 tiles in flight
    stage(As0, Bs0, 0);
    stage(As1, Bs1, 32);
    u16 *pa0 = As0, *pb0 = Bs0, *pa1 = As1, *pb1 = Bs1, *pa2 = As2, *pb2 = Bs2;

    for (int k0 = 0; k0 < K; k0 += 32) {
        if (k0 + 32 < K) {
            // tile t's 4 loads retired (tile t+1's 4 may remain in flight)
            asm volatile("s_waitcnt vmcnt(4)" ::: "memory");
        } else {
            asm volatile("s_waitcnt vmcnt(0)" ::: "memory");
        }
        __builtin_amdgcn_s_barrier();
        __builtin_amdgcn_sched_barrier(0);
        if (k0 + 64 < K) stage(pa2, pb2, k0 + 64);
        compute(pa0, pb0);
        u16* ta = pa0; pa0 = pa1; pa1 = pa2; pa2 = ta;
        u16* tb = pb0; pb0 = pb1; pb1 = pb2; pb2 = tb;
    }

#pragma unroll
    for (int r = 0; r < 4; ++r) {
#pragma unroll
        for (int c = 0; c < 4; ++c) {
            const int col = n0 + ncol + c * 16 + l16;
            const float bv = bias[col];
#pragma unroll
            for (int reg = 0; reg < 4; ++reg) {
                const int row = m0 + mrow + r * 16 + quad * 4 + reg;
                float val = acc[r][c][reg] + bv;
                if (MODE == 0) {
                    Cout[(size_t)row * N + col] = val;
                } else {
                    const int which = col >> 10;
                    const int rem   = col & 1023;
                    const int h     = rem >> 6;
                    const int d     = rem & 63;
                    const int b     = row >> 11;
                    const int n     = row & 2047;
                    if (which == 0) val *= KQ_SCALE;   // fold softmax scale + log2e into Q
                    u16* dst = (which == 0) ? qOut : (which == 1) ? kOut : vOut;
                    dst[(((size_t)(b * kH + h)) * kN + n) * kD + d] = f2bf(val);
                }
            }
        }
    }
}

// ------------------------------------------------- MFMA attention (bf16)
// R8-proven version (best measured: 124 us), byte-for-byte. Block = 128
// q-rows of one (b,h); 4 waves, wave w owns q-rows w*32..+32. Double-
// buffered LDS (64 KB), one barrier per KV-tile. P stays in registers
// (permuted-k trick); row-sums via ones-MFMA; Q pre-scaled by 0.125*log2e.
// Occupancy ladder CLOSED by measurement: body needs ~92 VGPR ->
// (256,2)=92 VGPR OK; (256,4) capped VGPR at 64 -> 534 MB spill traffic,
// 241 us (R12); 64-row geometry at cap 128 also spilled (R11, 154 us).
__global__ __launch_bounds__(256, 2) void attn_mfma_kernel(
    const u16* __restrict__ q, const u16* __restrict__ k,
    const u16* __restrict__ v, const u32* __restrict__ mbits,
    u16* __restrict__ out)   // bf16 ao [B,N,C]
{
    __shared__ u16 Ks[2][128 * 64];   // 32 KB  [key][d], chunk ^= (key&7)
    __shared__ u16 Vt[2][64 * 128];   // 32 KB  [d][key-permuted], chunk ^= (d&15)

    const int t    = threadIdx.x;
    const int w    = t >> 6;
    const int lane = t & 63;
    const int quad = lane >> 4;
    const int l16  = lane & 15;

    const int bh    = blockIdx.x >> 4;          // 16 q-tiles of 128 rows
    const int tile0 = (blockIdx.x & 15) * 128;
    const int b     = bh >> 4;
    const int h     = bh & 15;

    const u16* qb = q + (size_t)bh * kN * kD;
    const u16* kb = k + (size_t)bh * kN * kD;
    const u16* vb = v + (size_t)bh * kN * kD;

    // Q B-fragments for 2 strips: lane holds Q[qrow][d = quad*8 + j]
    const int qrow0 = tile0 + w * 32 + l16;
    const int qrow1 = qrow0 + 16;
    v8bf qf[2][2];
    qf[0][0] = *(const v8bf*)(qb + (size_t)qrow0 * kD + quad * 8);
    qf[0][1] = *(const v8bf*)(qb + (size_t)qrow0 * kD + 32 + quad * 8);
    qf[1][0] = *(const v8bf*)(qb + (size_t)qrow1 * kD + quad * 8);
    qf[1][1] = *(const v8bf*)(qb + (size_t)qrow1 * kD + 32 + quad * 8);

    // staging geometry (constant per thread)
    // K: 2 rows x 32 dims per thread (4x 16B swizzled b128 writes)
    const int skr  = t >> 1;           // K row 0..127
    const int skh  = t & 1;            // K half (32 elems)
    // V: permuted 8 keys x 4 dims per thread -> 4x b128 transposed writes.
    const int vg   = t >> 4;           // frag chunk 0..15
    const int vdq  = t & 15;           // dim quad (dims vdq*4..+3)
    const int vrow0 = (vg >> 2) * 32 + (vg & 3) * 4;

    const u16* kp = kb + (size_t)skr * kD + skh * 32;
    const u16* vp = vb + (size_t)vrow0 * kD + vdq * 4;
    const uint4* mp0 = (const uint4*)(mbits + ((size_t)b * kN + qrow0) * 64);
    const uint4* mp1 = (const uint4*)(mbits + ((size_t)b * kN + qrow1) * 64);

    u16x8 kpre[4];
    u16x4 vpre[8];
    uint4 mpre0, mpre1;
    auto issue_prefetch = [&]() {
#pragma unroll
        for (int i = 0; i < 4; ++i)
            kpre[i] = *(const u16x8*)(kp + i * 8);
#pragma unroll
        for (int i = 0; i < 8; ++i)
            vpre[i] = *(const u16x4*)(vp + (i < 4 ? i * 64 : 1024 + (i - 4) * 64));
        mpre0 = *mp0; mpre1 = *mp1;
        kp += 128 * kD; vp += 128 * kD; ++mp0; ++mp1;
    };

    v8bf onesf;
#pragma unroll
    for (int j = 0; j < 8; ++j) onesf[j] = (__bf16)1.0f;

    v4f oacc[2][4];
    v4f rsacc[2];
#pragma unroll
    for (int qs = 0; qs < 2; ++qs) {
        rsacc[qs] = (v4f){0.f, 0.f, 0.f, 0.f};
#pragma unroll
        for (int i = 0; i < 4; ++i) oacc[qs][i] = (v4f){0.f, 0.f, 0.f, 0.f};
    }

    issue_prefetch();   // tile 0

    for (int kt = 0; kt < kN / 128; ++kt) {
        u16* KsB = Ks[kt & 1];
        u16* VtB = Vt[kt & 1];

        // ---- stage tile kt from regs into buf[kt&1]
        {
            const int cb = skh * 4;
            u16* drow = &KsB[skr * 64];
#pragma unroll
            for (int i = 0; i < 4; ++i)
                *(u16x8*)(&drow[((cb + i) ^ (skr & 7)) * 8]) = kpre[i];
        }
        {
#pragma unroll
            for (int dd = 0; dd < 4; ++dd) {
                const int d = vdq * 4 + dd;
                u16x8 col;
#pragma unroll
                for (int j = 0; j < 8; ++j) col[j] = vpre[j][dd];
                *(u16x8*)(&VtB[d * 128 + ((vg ^ (d & 15)) * 8)]) = col;
            }
        }
        const uint4 mc0 = mpre0, mc1 = mpre1;
        if (kt + 1 < kN / 128) issue_prefetch();   // regs free after ds_writes issue

        __syncthreads();   // publish buf[kt&1]; WAR covered by prev barrier

        const u32 mwa[2][4] = {{mc0.x, mc0.y, mc0.z, mc0.w},
                               {mc1.x, mc1.y, mc1.z, mc1.w}};
        v8bf pa[2][4];     // P A-fragments, built directly in registers

        // ---- S^T + softmax: lane gets s[reg] = S[key=nb*16+quad*4+reg][q=l16]
#pragma unroll
        for (int nb = 0; nb < 8; ++nb) {
            const int krow = nb * 16 + l16;
            const v8bf kf0 = *(const v8bf*)(&KsB[krow * 64 + ((quad       ^ (krow & 7)) * 8)]);
            const v8bf kf1 = *(const v8bf*)(&KsB[krow * 64 + (((quad + 4) ^ (krow & 7)) * 8)]);
#pragma unroll
            for (int qs = 0; qs < 2; ++qs) {
                v4f s = (v4f){0.f, 0.f, 0.f, 0.f};
                s = __builtin_amdgcn_mfma_f32_16x16x32_bf16(kf0, qf[qs][0], s, 0, 0, 0);
                s = __builtin_amdgcn_mfma_f32_16x16x32_bf16(kf1, qf[qs][1], s, 0, 0, 0);

                const u32 m4 = (mwa[qs][nb >> 1] >> ((nb & 1) * 16 + quad * 4)) & 0xFu;
                float e0 = fast_exp2(s[0]);
                float e1 = fast_exp2(s[1]);
                float e2 = fast_exp2(s[2]);
                float e3 = fast_exp2(s[3]);
                e0 = (m4 & 1u) ? 0.f : e0;
                e1 = (m4 & 2u) ? 0.f : e1;
                e2 = (m4 & 4u) ? 0.f : e2;
                e3 = (m4 & 8u) ? 0.f : e3;

                pa[qs][nb >> 1][(nb & 1) * 4 + 0] = (__bf16)e0;
                pa[qs][nb >> 1][(nb & 1) * 4 + 1] = (__bf16)e1;
                pa[qs][nb >> 1][(nb & 1) * 4 + 2] = (__bf16)e2;
                pa[qs][nb >> 1][(nb & 1) * 4 + 3] = (__bf16)e3;
            }
        }

        __builtin_amdgcn_s_setprio(1);
        // row-sums via ones-MFMA: rsacc row layout == oacc row layout
#pragma unroll
        for (int qs = 0; qs < 2; ++qs)
#pragma unroll
            for (int ks = 0; ks < 4; ++ks)
                rsacc[qs] = __builtin_amdgcn_mfma_f32_16x16x32_bf16(
                    pa[qs][ks], onesf, rsacc[qs], 0, 0, 0);
        // ---- PV: O[q][d] += P(32x128) @ V^T
#pragma unroll
        for (int ks = 0; ks < 4; ++ks)
#pragma unroll
            for (int db = 0; db < 4; ++db) {
                const int d = db * 16 + l16;
                const v8bf vf = *(const v8bf*)(&VtB[d * 128 + (((ks * 4 + quad) ^ (d & 15)) * 8)]);
#pragma unroll
                for (int qs = 0; qs < 2; ++qs)
                    oacc[qs][db] = __builtin_amdgcn_mfma_f32_16x16x32_bf16(
                        pa[qs][ks], vf, oacc[qs][db], 0, 0, 0);
            }
        __builtin_amdgcn_s_setprio(0);
    }

    // ---- normalize + store: rsacc rows already match oacc rows (quad*4+reg)
#pragma unroll
    for (int qs = 0; qs < 2; ++qs) {
        float inv[4];
#pragma unroll
        for (int reg = 0; reg < 4; ++reg) inv[reg] = 1.f / rsacc[qs][reg];
#pragma unroll
        for (int db = 0; db < 4; ++db)
#pragma unroll
            for (int reg = 0; reg < 4; ++reg) {
                const int row = tile0 + w * 32 + qs * 16 + quad * 4 + reg;
                const int col = h * 64 + db * 16 + l16;
                out[((size_t)(b * kN + row)) * kC + col] = f2bf(oacc[qs][db][reg] * inv[reg]);
            }
    }
}

// ------------------------------------------------------------------ launch
extern "C" void kernel_launch(void* const* d_in, const int* in_sizes, int n_in,
                              void* d_out, int out_size, void* d_ws, size_t ws_size,
                              hipStream_t stream)
{
    const float* x     = (const float*)d_in[0];
    const int*   mask  = (const int*)d_in[1];
    const float* Wqkv  = (const float*)d_in[2];
    const float* bqkv  = (const float*)d_in[3];
    const float* Wproj = (const float*)d_in[4];
    const float* bproj = (const float*)d_in[5];
    float* out = (float*)d_out;

    const size_t nx = (size_t)kB * kN * kC;
    const size_t qkv_elems = (size_t)kB * kH * kN * kD;
    u16* xb     = (u16*)d_ws;
    u16* qbuf   = xb + nx;
    u16* kbuf   = qbuf + qkv_elems;
    u16* vbuf   = kbuf + qkv_elems;
    u16* aob    = vbuf + qkv_elems;
    u16* Wqkvt  = aob + nx;
    u16* Wprojt = Wqkvt + (size_t)3 * kC * kC;
    u32* mbits  = (u32*)(Wprojt + (size_t)kC * kC);   // 2 MB bitmask

    maskpack_kernel<<<dim3(2048), dim3(256), 0, stream>>>(mask, mbits);
    cast_bf16_kernel<<<dim3(nx / 1024), dim3(256), 0, stream>>>(x, xb);
    tpose_cast_kernel<<<dim3(3 * kC / 64, kC / 64), dim3(256), 0, stream>>>(
        Wqkv, Wqkvt, kC, 3 * kC);
    tpose_cast_kernel<<<dim3(kC / 64, kC / 64), dim3(256), 0, stream>>>(
        Wproj, Wprojt, kC, kC);

    // 1-D grids (XCD swizzle inside): nwg = (N/128)*(M/128), % 8 == 0
    gemm_mfma_kernel<1><<<dim3((3 * kC / 128) * (kB * kN / 128)), dim3(256), 0, stream>>>(
        xb, Wqkvt, bqkv, nullptr, qbuf, kbuf, vbuf, kB * kN, 3 * kC, kC);

    attn_mfma_kernel<<<dim3(kB * kH * (kN / 128)), dim3(256), 0, stream>>>(
        qbuf, kbuf, vbuf, mbits, aob);

    gemm_mfma_kernel<0><<<dim3((kC / 128) * (kB * kN / 128)), dim3(256), 0, stream>>>(
        aob, Wprojt, bproj, out, nullptr, nullptr, nullptr, kB * kN, kC, kC);
}

// Round 14
// 368.243 us; speedup vs baseline: 1.3408x; 1.0058x over previous
//
#include <hip/hip_runtime.h>
#include <cstdint>
#include <cstddef>

constexpr int kC = 1024;   // DIM
constexpr int kH = 16;     // heads
constexpr int kB = 4;      // batch
constexpr int kN = 2048;   // seq
constexpr int kD = 64;     // head dim

// softmax scale folded into Q at the QKV-GEMM epilogue: 0.125 * log2(e)
#define KQ_SCALE 0.18033688011112042f

typedef unsigned short u16;
typedef unsigned int   u32;
typedef unsigned long long u64;
typedef __bf16 v8bf  __attribute__((ext_vector_type(8)));
typedef float  v4f   __attribute__((ext_vector_type(4)));
typedef u16    u16x8 __attribute__((ext_vector_type(8)));
typedef u16    u16x4 __attribute__((ext_vector_type(4)));

__device__ inline u16 f2bf(float f) {
    union { float f; unsigned u; } v; v.f = f;
    unsigned r = v.u + 0x7FFFu + ((v.u >> 16) & 1u);   // RNE
    return (u16)(r >> 16);
}

__device__ inline float fast_exp2(float x) {
#if __has_builtin(__builtin_amdgcn_exp2f)
    return __builtin_amdgcn_exp2f(x);          // bare v_exp_f32
#else
    return __expf(x * 0.6931471805599453f);
#endif
}

// async 16B global -> LDS (wave-uniform LDS base + lane*16)
__device__ inline void gl2lds16(const u16* g, u16* l) {
    __builtin_amdgcn_global_load_lds(
        (const __attribute__((address_space(1))) void*)g,
        (__attribute__((address_space(3))) void*)l, 16, 0, 0);
}

// ---------------------------------------------------------------- casts
__global__ __launch_bounds__(256) void cast_bf16_kernel(
    const float* __restrict__ in, u16* __restrict__ outp)
{
    const int i = blockIdx.x * 256 + threadIdx.x;
    const float4 f = ((const float4*)in)[i];
    u16x4 o;
    o.x = f2bf(f.x); o.y = f2bf(f.y); o.z = f2bf(f.z); o.w = f2bf(f.w);
    ((u16x4*)outp)[i] = o;
}

// W [R][Cc] fp32 -> Wt [Cc][R] bf16, 64x64 LDS tiles
__global__ __launch_bounds__(256) void tpose_cast_kernel(
    const float* __restrict__ W, u16* __restrict__ Wt, int R, int Cc)
{
    __shared__ u16 tile[64][65];
    const int c0 = blockIdx.x * 64;
    const int r0 = blockIdx.y * 64;
    const int t  = threadIdx.x;
#pragma unroll
    for (int it = 0; it < 16; ++it) {
        const int r = it * 4 + (t >> 6);
        const int c = t & 63;
        tile[c][r] = f2bf(W[(size_t)(r0 + r) * Cc + c0 + c]);
    }
    __syncthreads();
#pragma unroll
    for (int it = 0; it < 16; ++it) {
        const int rr = it * 4 + (t >> 6);
        const int cc = t & 63;
        Wt[(size_t)(c0 + rr) * R + r0 + cc] = tile[rr][cc];
    }
}

// ------------------------------------------------------------ mask pack
// Grid-strided: 2048 blocks. Row-bitmap: row (b*N+q) is 2048 bits
// (64 u32), bit k set iff masked. (R5-proven version.)
__global__ __launch_bounds__(256) void maskpack_kernel(
    const int* __restrict__ mask, u32* __restrict__ bits)
{
    const int lane = threadIdx.x & 63;
    const int wv   = threadIdx.x >> 6;
    const int nseg = kB * kN * 32;
    for (int seg = blockIdx.x * 4 + wv; seg < nseg; seg += gridDim.x * 4) {
        const size_t row = (size_t)(seg >> 5);   // b*N + q
        const int s = seg & 31;                  // 64-key segment within row
        const int m = mask[row * kN + s * 64 + lane];
        const u64 bal = __ballot(m != 0);
        if (lane == 0) ((u64*)bits)[row * 32 + s] = bal;
    }
}

// ---------------------------------------------------- bf16 MFMA GEMM
// C[M,N] = A[M,K] @ Bt[N,K]^T + bias.  128x128 tile, BK=32, 4 waves.
// 3-buffer / 2-ahead pipeline with COUNTED vmcnt + raw s_barrier (T3/T4).
// R5/R10/R13-proven config — unchanged.
template <int MODE>
__global__ __launch_bounds__(256, 3) void gemm_mfma_kernel(
    const u16* __restrict__ A, const u16* __restrict__ Bt,
    const float* __restrict__ bias, float* __restrict__ Cout,
    u16* __restrict__ qOut, u16* __restrict__ kOut, u16* __restrict__ vOut,
    int M, int N, int K)
{
    __shared__ u16 As0[128 * 32], Bs0[128 * 32];
    __shared__ u16 As1[128 * 32], Bs1[128 * 32];
    __shared__ u16 As2[128 * 32], Bs2[128 * 32];
    const int t    = threadIdx.x;
    const int w    = t >> 6;
    const int lane = t & 63;
    const int quad = lane >> 4;
    const int l16  = lane & 15;

    // XCD-chunked bijective swizzle (nwg % 8 == 0), column-major walk
    const int nby = M >> 7;
    const int q8  = (int)gridDim.x >> 3;
    const int bid = (int)blockIdx.x;
    const int swz = (bid & 7) * q8 + (bid >> 3);
    const int m0  = (swz % nby) * 128;
    const int n0  = (swz / nby) * 128;

    const int sr  = lane >> 2;                              // staging row in 16
    const int scs = ((lane & 3) ^ ((sr >> 1) & 3)) * 8;     // swizzled src chunk
    const u16* Ag0 = A  + (size_t)(m0 + 32 * w      + sr) * K + scs;
    const u16* Ag1 = A  + (size_t)(m0 + 32 * w + 16 + sr) * K + scs;
    const u16* Bg0 = Bt + (size_t)(n0 + 32 * w      + sr) * K + scs;
    const u16* Bg1 = Bt + (size_t)(n0 + 32 * w + 16 + sr) * K + scs;

    v4f acc[4][4];
#pragma unroll
    for (int r = 0; r < 4; ++r)
#pragma unroll
        for (int c = 0; c < 4; ++c) acc[r][c] = (v4f){0.f, 0.f, 0.f, 0.f};

    const int mrow = (w >> 1) * 64;
    const int ncol = (w & 1) * 64;
    const int pch  = (quad ^ ((l16 >> 1) & 3)) * 8;         // swizzled read chunk

    auto stage = [&](u16* Asb, u16* Bsb, int k0) {
        gl2lds16(Ag0 + k0, Asb + (32 * w) * 32);
        gl2lds16(Ag1 + k0, Asb + (32 * w + 16) * 32);
        gl2lds16(Bg0 + k0, Bsb + (32 * w) * 32);
        gl2lds16(Bg1 + k0, Bsb + (32 * w + 16) * 32);
    };
    auto compute = [&](const u16* Asb, const u16* Bsb) {
        v8bf af[4], bfr[4];
#pragma unroll
        for (int r = 0; r < 4; ++r)
            af[r] = *(const v8bf*)(Asb + (mrow + r * 16 + l16) * 32 + pch);
#pragma unroll
        for (int c = 0; c < 4; ++c)
            bfr[c] = *(const v8bf*)(Bsb + (ncol + c * 16 + l16) * 32 + pch);
        __builtin_amdgcn_s_setprio(1);
#pragma unroll
        for (int r = 0; r < 4; ++r)
#pragma unroll
            for (int c = 0; c < 4; ++c)
                acc[r][c] = __builtin_amdgcn_mfma_f32_16x16x32_bf16(
                    af[r], bfr[c], acc[r][c], 0, 0, 0);
        __builtin_amdgcn_s_setprio(0);
    };

    // prologue: 2 tiles in flight
    stage(As0, Bs0, 0);
    stage(As1, Bs1, 32);
    u16 *pa0 = As0, *pb0 = Bs0, *pa1 = As1, *pb1 = Bs1, *pa2 = As2, *pb2 = Bs2;

    for (int k0 = 0; k0 < K; k0 += 32) {
        if (k0 + 32 < K) {
            // tile t's 4 loads retired (tile t+1's 4 may remain in flight)
            asm volatile("s_waitcnt vmcnt(4)" ::: "memory");
        } else {
            asm volatile("s_waitcnt vmcnt(0)" ::: "memory");
        }
        __builtin_amdgcn_s_barrier();
        __builtin_amdgcn_sched_barrier(0);
        if (k0 + 64 < K) stage(pa2, pb2, k0 + 64);
        compute(pa0, pb0);
        u16* ta = pa0; pa0 = pa1; pa1 = pa2; pa2 = ta;
        u16* tb = pb0; pb0 = pb1; pb1 = pb2; pb2 = tb;
    }

#pragma unroll
    for (int r = 0; r < 4; ++r) {
#pragma unroll
        for (int c = 0; c < 4; ++c) {
            const int col = n0 + ncol + c * 16 + l16;
            const float bv = bias[col];
#pragma unroll
            for (int reg = 0; reg < 4; ++reg) {
                const int row = m0 + mrow + r * 16 + quad * 4 + reg;
                float val = acc[r][c][reg] + bv;
                if (MODE == 0) {
                    Cout[(size_t)row * N + col] = val;
                } else {
                    const int which = col >> 10;
                    const int rem   = col & 1023;
                    const int h     = rem >> 6;
                    const int d     = rem & 63;
                    const int b     = row >> 11;
                    const int n     = row & 2047;
                    if (which == 0) val *= KQ_SCALE;   // fold softmax scale + log2e into Q
                    u16* dst = (which == 0) ? qOut : (which == 1) ? kOut : vOut;
                    dst[(((size_t)(b * kH + h)) * kN + n) * kD + d] = f2bf(val);
                }
            }
        }
    }
}

// ------------------------------------------------- MFMA attention (bf16)
// R13 body + CROSS-TILE PV PIPELINE (T15-analog): PV(t-1) now runs between
// stage(t)'s ds_writes and barrier(t) — it consumes only registers (pa
// from tile t-1) and the OTHER LDS buffer (published at barrier(t-1)),
// so 40 MFMA fill the staging-latency + barrier-convergence gap.
// Hazards (one barrier/tile preserved): stage(t) writes buf[t&1], PV(t-1)
// reads buf[(t-1)&1] — disjoint. Cross-wave WAR (A's stage(t) vs B's
// PV(t-2), same buffer) separated by barrier(t-1). RAW on S(t) by
// barrier(t). Epilogue PV(last) after loop. pa persists one iteration:
// +32 VGPR (~124 total), still 2 blocks/CU — no R11/R12-style spill.
__global__ __launch_bounds__(256, 2) void attn_mfma_kernel(
    const u16* __restrict__ q, const u16* __restrict__ k,
    const u16* __restrict__ v, const u32* __restrict__ mbits,
    u16* __restrict__ out)   // bf16 ao [B,N,C]
{
    __shared__ u16 Ks[2][128 * 64];   // 32 KB  [key][d], chunk ^= (key&7)
    __shared__ u16 Vt[2][64 * 128];   // 32 KB  [d][key-permuted], chunk ^= (d&15)

    const int t    = threadIdx.x;
    const int w    = t >> 6;
    const int lane = t & 63;
    const int quad = lane >> 4;
    const int l16  = lane & 15;

    const int bh    = blockIdx.x >> 4;          // 16 q-tiles of 128 rows
    const int tile0 = (blockIdx.x & 15) * 128;
    const int b     = bh >> 4;
    const int h     = bh & 15;

    const u16* qb = q + (size_t)bh * kN * kD;
    const u16* kb = k + (size_t)bh * kN * kD;
    const u16* vb = v + (size_t)bh * kN * kD;

    // Q B-fragments for 2 strips: lane holds Q[qrow][d = quad*8 + j]
    const int qrow0 = tile0 + w * 32 + l16;
    const int qrow1 = qrow0 + 16;
    v8bf qf[2][2];
    qf[0][0] = *(const v8bf*)(qb + (size_t)qrow0 * kD + quad * 8);
    qf[0][1] = *(const v8bf*)(qb + (size_t)qrow0 * kD + 32 + quad * 8);
    qf[1][0] = *(const v8bf*)(qb + (size_t)qrow1 * kD + quad * 8);
    qf[1][1] = *(const v8bf*)(qb + (size_t)qrow1 * kD + 32 + quad * 8);

    // staging geometry (constant per thread)
    // K: 2 rows x 32 dims per thread (4x 16B swizzled b128 writes)
    const int skr  = t >> 1;           // K row 0..127
    const int skh  = t & 1;            // K half (32 elems)
    // V: permuted 8 keys x 4 dims per thread -> 4x b128 transposed writes.
    const int vg   = t >> 4;           // frag chunk 0..15
    const int vdq  = t & 15;           // dim quad (dims vdq*4..+3)
    const int vrow0 = (vg >> 2) * 32 + (vg & 3) * 4;

    const u16* kp = kb + (size_t)skr * kD + skh * 32;
    const u16* vp = vb + (size_t)vrow0 * kD + vdq * 4;
    const uint4* mp0 = (const uint4*)(mbits + ((size_t)b * kN + qrow0) * 64);
    const uint4* mp1 = (const uint4*)(mbits + ((size_t)b * kN + qrow1) * 64);

    u16x8 kpre[4];
    u16x4 vpre[8];
    uint4 mpre0, mpre1;
    auto issue_prefetch = [&]() {
#pragma unroll
        for (int i = 0; i < 4; ++i)
            kpre[i] = *(const u16x8*)(kp + i * 8);
#pragma unroll
        for (int i = 0; i < 8; ++i)
            vpre[i] = *(const u16x4*)(vp + (i < 4 ? i * 64 : 1024 + (i - 4) * 64));
        mpre0 = *mp0; mpre1 = *mp1;
        kp += 128 * kD; vp += 128 * kD; ++mp0; ++mp1;
    };

    v8bf onesf;
#pragma unroll
    for (int j = 0; j < 8; ++j) onesf[j] = (__bf16)1.0f;

    v4f oacc[2][4];
    v4f rsacc[2];
#pragma unroll
    for (int qs = 0; qs < 2; ++qs) {
        rsacc[qs] = (v4f){0.f, 0.f, 0.f, 0.f};
#pragma unroll
        for (int i = 0; i < 4; ++i) oacc[qs][i] = (v4f){0.f, 0.f, 0.f, 0.f};
    }

    issue_prefetch();   // tile 0

    v8bf pa[2][4];      // P A-fragments of the PREVIOUS tile (persist 1 iter)
    constexpr int NT = kN / 128;

    for (int kt = 0; kt < NT; ++kt) {
        u16* KsB = Ks[kt & 1];
        u16* VtB = Vt[kt & 1];
        u16* VtP = Vt[(kt ^ 1) & 1];   // previous tile's V (valid for kt>0)

        // ---- stage tile kt from regs into buf[kt&1]
        {
            const int cb = skh * 4;
            u16* drow = &KsB[skr * 64];
#pragma unroll
            for (int i = 0; i < 4; ++i)
                *(u16x8*)(&drow[((cb + i) ^ (skr & 7)) * 8]) = kpre[i];
        }
        {
#pragma unroll
            for (int dd = 0; dd < 4; ++dd) {
                const int d = vdq * 4 + dd;
                u16x8 col;
#pragma unroll
                for (int j = 0; j < 8; ++j) col[j] = vpre[j][dd];
                *(u16x8*)(&VtB[d * 128 + ((vg ^ (d & 15)) * 8)]) = col;
            }
        }
        const uint4 mc0 = mpre0, mc1 = mpre1;
        if (kt + 1 < NT) issue_prefetch();   // regs free after ds_writes issue

        // ---- PV(kt-1): registers + previous buffer; overlaps staging+barrier
        if (kt > 0) {
            __builtin_amdgcn_s_setprio(1);
#pragma unroll
            for (int qs = 0; qs < 2; ++qs)
#pragma unroll
                for (int ks = 0; ks < 4; ++ks)
                    rsacc[qs] = __builtin_amdgcn_mfma_f32_16x16x32_bf16(
                        pa[qs][ks], onesf, rsacc[qs], 0, 0, 0);
#pragma unroll
            for (int ks = 0; ks < 4; ++ks)
#pragma unroll
                for (int db = 0; db < 4; ++db) {
                    const int d = db * 16 + l16;
                    const v8bf vf = *(const v8bf*)(&VtP[d * 128 + (((ks * 4 + quad) ^ (d & 15)) * 8)]);
#pragma unroll
                    for (int qs = 0; qs < 2; ++qs)
                        oacc[qs][db] = __builtin_amdgcn_mfma_f32_16x16x32_bf16(
                            pa[qs][ks], vf, oacc[qs][db], 0, 0, 0);
                }
            __builtin_amdgcn_s_setprio(0);
        }

        __syncthreads();   // publish buf[kt&1]; WAR covered by prev barrier

        const u32 mwa[2][4] = {{mc0.x, mc0.y, mc0.z, mc0.w},
                               {mc1.x, mc1.y, mc1.z, mc1.w}};

        // ---- S^T + softmax: lane gets s[reg] = S[key=nb*16+quad*4+reg][q=l16]
#pragma unroll
        for (int nb = 0; nb < 8; ++nb) {
            const int krow = nb * 16 + l16;
            const v8bf kf0 = *(const v8bf*)(&KsB[krow * 64 + ((quad       ^ (krow & 7)) * 8)]);
            const v8bf kf1 = *(const v8bf*)(&KsB[krow * 64 + (((quad + 4) ^ (krow & 7)) * 8)]);
#pragma unroll
            for (int qs = 0; qs < 2; ++qs) {
                v4f s = (v4f){0.f, 0.f, 0.f, 0.f};
                s = __builtin_amdgcn_mfma_f32_16x16x32_bf16(kf0, qf[qs][0], s, 0, 0, 0);
                s = __builtin_amdgcn_mfma_f32_16x16x32_bf16(kf1, qf[qs][1], s, 0, 0, 0);

                const u32 m4 = (mwa[qs][nb >> 1] >> ((nb & 1) * 16 + quad * 4)) & 0xFu;
                float e0 = fast_exp2(s[0]);
                float e1 = fast_exp2(s[1]);
                float e2 = fast_exp2(s[2]);
                float e3 = fast_exp2(s[3]);
                e0 = (m4 & 1u) ? 0.f : e0;
                e1 = (m4 & 2u) ? 0.f : e1;
                e2 = (m4 & 4u) ? 0.f : e2;
                e3 = (m4 & 8u) ? 0.f : e3;

                pa[qs][nb >> 1][(nb & 1) * 4 + 0] = (__bf16)e0;
                pa[qs][nb >> 1][(nb & 1) * 4 + 1] = (__bf16)e1;
                pa[qs][nb >> 1][(nb & 1) * 4 + 2] = (__bf16)e2;
                pa[qs][nb >> 1][(nb & 1) * 4 + 3] = (__bf16)e3;
            }
        }
    }

    // ---- epilogue: PV for the last tile (registers + published buffer)
    {
        u16* VtP = Vt[(NT - 1) & 1];
        __builtin_amdgcn_s_setprio(1);
#pragma unroll
        for (int qs = 0; qs < 2; ++qs)
#pragma unroll
            for (int ks = 0; ks < 4; ++ks)
                rsacc[qs] = __builtin_amdgcn_mfma_f32_16x16x32_bf16(
                    pa[qs][ks], onesf, rsacc[qs], 0, 0, 0);
#pragma unroll
        for (int ks = 0; ks < 4; ++ks)
#pragma unroll
            for (int db = 0; db < 4; ++db) {
                const int d = db * 16 + l16;
                const v8bf vf = *(const v8bf*)(&VtP[d * 128 + (((ks * 4 + quad) ^ (d & 15)) * 8)]);
#pragma unroll
                for (int qs = 0; qs < 2; ++qs)
                    oacc[qs][db] = __builtin_amdgcn_mfma_f32_16x16x32_bf16(
                        pa[qs][ks], vf, oacc[qs][db], 0, 0, 0);
            }
        __builtin_amdgcn_s_setprio(0);
    }

    // ---- normalize + store: rsacc rows already match oacc rows (quad*4+reg)
#pragma unroll
    for (int qs = 0; qs < 2; ++qs) {
        float inv[4];
#pragma unroll
        for (int reg = 0; reg < 4; ++reg) inv[reg] = 1.f / rsacc[qs][reg];
#pragma unroll
        for (int db = 0; db < 4; ++db)
#pragma unroll
            for (int reg = 0; reg < 4; ++reg) {
                const int row = tile0 + w * 32 + qs * 16 + quad * 4 + reg;
                const int col = h * 64 + db * 16 + l16;
                out[((size_t)(b * kN + row)) * kC + col] = f2bf(oacc[qs][db][reg] * inv[reg]);
            }
    }
}

// ------------------------------------------------------------------ launch
extern "C" void kernel_launch(void* const* d_in, const int* in_sizes, int n_in,
                              void* d_out, int out_size, void* d_ws, size_t ws_size,
                              hipStream_t stream)
{
    const float* x     = (const float*)d_in[0];
    const int*   mask  = (const int*)d_in[1];
    const float* Wqkv  = (const float*)d_in[2];
    const float* bqkv  = (const float*)d_in[3];
    const float* Wproj = (const float*)d_in[4];
    const float* bproj = (const float*)d_in[5];
    float* out = (float*)d_out;

    const size_t nx = (size_t)kB * kN * kC;
    const size_t qkv_elems = (size_t)kB * kH * kN * kD;
    u16* xb     = (u16*)d_ws;
    u16* qbuf   = xb + nx;
    u16* kbuf   = qbuf + qkv_elems;
    u16* vbuf   = kbuf + qkv_elems;
    u16* aob    = vbuf + qkv_elems;
    u16* Wqkvt  = aob + nx;
    u16* Wprojt = Wqkvt + (size_t)3 * kC * kC;
    u32* mbits  = (u32*)(Wprojt + (size_t)kC * kC);   // 2 MB bitmask

    maskpack_kernel<<<dim3(2048), dim3(256), 0, stream>>>(mask, mbits);
    cast_bf16_kernel<<<dim3(nx / 1024), dim3(256), 0, stream>>>(x, xb);
    tpose_cast_kernel<<<dim3(3 * kC / 64, kC / 64), dim3(256), 0, stream>>>(
        Wqkv, Wqkvt, kC, 3 * kC);
    tpose_cast_kernel<<<dim3(kC / 64, kC / 64), dim3(256), 0, stream>>>(
        Wproj, Wprojt, kC, kC);

    // 1-D grids (XCD swizzle inside): nwg = (N/128)*(M/128), % 8 == 0
    gemm_mfma_kernel<1><<<dim3((3 * kC / 128) * (kB * kN / 128)), dim3(256), 0, stream>>>(
        xb, Wqkvt, bqkv, nullptr, qbuf, kbuf, vbuf, kB * kN, 3 * kC, kC);

    attn_mfma_kernel<<<dim3(kB * kH * (kN / 128)), dim3(256), 0, stream>>>(
        qbuf, kbuf, vbuf, mbits, aob);

    gemm_mfma_kernel<0><<<dim3((kC / 128) * (kB * kN / 128)), dim3(256), 0, stream>>>(
        aob, Wprojt, bproj, out, nullptr, nullptr, nullptr, kB * kN, kC, kC);
}

// Round 15
// 366.042 us; speedup vs baseline: 1.3489x; 1.0060x over previous
//
#include <hip/hip_runtime.h>
#include <cstdint>
#include <cstddef>

constexpr int kC = 1024;   // DIM
constexpr int kH = 16;     // heads
constexpr int kB = 4;      // batch
constexpr int kN = 2048;   // seq
constexpr int kD = 64;     // head dim

// softmax scale folded into Q at the QKV-GEMM epilogue: 0.125 * log2(e)
#define KQ_SCALE 0.18033688011112042f

typedef unsigned short u16;
typedef unsigned int   u32;
typedef unsigned long long u64;
typedef __bf16 v8bf  __attribute__((ext_vector_type(8)));
typedef float  v4f   __attribute__((ext_vector_type(4)));
typedef u16    u16x8 __attribute__((ext_vector_type(8)));
typedef u16    u16x4 __attribute__((ext_vector_type(4)));

__device__ inline u16 f2bf(float f) {
    union { float f; unsigned u; } v; v.f = f;
    unsigned r = v.u + 0x7FFFu + ((v.u >> 16) & 1u);   // RNE
    return (u16)(r >> 16);
}

__device__ inline float fast_exp2(float x) {
#if __has_builtin(__builtin_amdgcn_exp2f)
    return __builtin_amdgcn_exp2f(x);          // bare v_exp_f32
#else
    return __expf(x * 0.6931471805599453f);
#endif
}

// async 16B global -> LDS (wave-uniform LDS base + lane*16)
__device__ inline void gl2lds16(const u16* g, u16* l) {
    __builtin_amdgcn_global_load_lds(
        (const __attribute__((address_space(1))) void*)g,
        (__attribute__((address_space(3))) void*)l, 16, 0, 0);
}

// ---------------------------------------------------------------- casts
__global__ __launch_bounds__(256) void cast_bf16_kernel(
    const float* __restrict__ in, u16* __restrict__ outp)
{
    const int i = blockIdx.x * 256 + threadIdx.x;
    const float4 f = ((const float4*)in)[i];
    u16x4 o;
    o.x = f2bf(f.x); o.y = f2bf(f.y); o.z = f2bf(f.z); o.w = f2bf(f.w);
    ((u16x4*)outp)[i] = o;
}

// W [R][Cc] fp32 -> Wt [Cc][R] bf16, 64x64 LDS tiles
__global__ __launch_bounds__(256) void tpose_cast_kernel(
    const float* __restrict__ W, u16* __restrict__ Wt, int R, int Cc)
{
    __shared__ u16 tile[64][65];
    const int c0 = blockIdx.x * 64;
    const int r0 = blockIdx.y * 64;
    const int t  = threadIdx.x;
#pragma unroll
    for (int it = 0; it < 16; ++it) {
        const int r = it * 4 + (t >> 6);
        const int c = t & 63;
        tile[c][r] = f2bf(W[(size_t)(r0 + r) * Cc + c0 + c]);
    }
    __syncthreads();
#pragma unroll
    for (int it = 0; it < 16; ++it) {
        const int rr = it * 4 + (t >> 6);
        const int cc = t & 63;
        Wt[(size_t)(c0 + rr) * R + r0 + cc] = tile[rr][cc];
    }
}

// ------------------------------------------------------------ mask pack
// Grid-strided: 2048 blocks. Row-bitmap: row (b*N+q) is 2048 bits
// (64 u32), bit k set iff masked. (R5-proven version.)
__global__ __launch_bounds__(256) void maskpack_kernel(
    const int* __restrict__ mask, u32* __restrict__ bits)
{
    const int lane = threadIdx.x & 63;
    const int wv   = threadIdx.x >> 6;
    const int nseg = kB * kN * 32;
    for (int seg = blockIdx.x * 4 + wv; seg < nseg; seg += gridDim.x * 4) {
        const size_t row = (size_t)(seg >> 5);   // b*N + q
        const int s = seg & 31;                  // 64-key segment within row
        const int m = mask[row * kN + s * 64 + lane];
        const u64 bal = __ballot(m != 0);
        if (lane == 0) ((u64*)bits)[row * 32 + s] = bal;
    }
}

// ---------------------------------------------------- bf16 MFMA GEMM
// C[M,N] = A[M,K] @ Bt[N,K]^T + bias.  128x128 tile, BK=32, 4 waves.
// 3-buffer / 2-ahead pipeline with COUNTED vmcnt + raw s_barrier (T3/T4).
// R5/R10/R13-proven config — unchanged.
template <int MODE>
__global__ __launch_bounds__(256, 3) void gemm_mfma_kernel(
    const u16* __restrict__ A, const u16* __restrict__ Bt,
    const float* __restrict__ bias, float* __restrict__ Cout,
    u16* __restrict__ qOut, u16* __restrict__ kOut, u16* __restrict__ vOut,
    int M, int N, int K)
{
    __shared__ u16 As0[128 * 32], Bs0[128 * 32];
    __shared__ u16 As1[128 * 32], Bs1[128 * 32];
    __shared__ u16 As2[128 * 32], Bs2[128 * 32];
    const int t    = threadIdx.x;
    const int w    = t >> 6;
    const int lane = t & 63;
    const int quad = lane >> 4;
    const int l16  = lane & 15;

    // XCD-chunked bijective swizzle (nwg % 8 == 0), column-major walk
    const int nby = M >> 7;
    const int q8  = (int)gridDim.x >> 3;
    const int bid = (int)blockIdx.x;
    const int swz = (bid & 7) * q8 + (bid >> 3);
    const int m0  = (swz % nby) * 128;
    const int n0  = (swz / nby) * 128;

    const int sr  = lane >> 2;                              // staging row in 16
    const int scs = ((lane & 3) ^ ((sr >> 1) & 3)) * 8;     // swizzled src chunk
    const u16* Ag0 = A  + (size_t)(m0 + 32 * w      + sr) * K + scs;
    const u16* Ag1 = A  + (size_t)(m0 + 32 * w + 16 + sr) * K + scs;
    const u16* Bg0 = Bt + (size_t)(n0 + 32 * w      + sr) * K + scs;
    const u16* Bg1 = Bt + (size_t)(n0 + 32 * w + 16 + sr) * K + scs;

    v4f acc[4][4];
#pragma unroll
    for (int r = 0; r < 4; ++r)
#pragma unroll
        for (int c = 0; c < 4; ++c) acc[r][c] = (v4f){0.f, 0.f, 0.f, 0.f};

    const int mrow = (w >> 1) * 64;
    const int ncol = (w & 1) * 64;
    const int pch  = (quad ^ ((l16 >> 1) & 3)) * 8;         // swizzled read chunk

    auto stage = [&](u16* Asb, u16* Bsb, int k0) {
        gl2lds16(Ag0 + k0, Asb + (32 * w) * 32);
        gl2lds16(Ag1 + k0, Asb + (32 * w + 16) * 32);
        gl2lds16(Bg0 + k0, Bsb + (32 * w) * 32);
        gl2lds16(Bg1 + k0, Bsb + (32 * w + 16) * 32);
    };
    auto compute = [&](const u16* Asb, const u16* Bsb) {
        v8bf af[4], bfr[4];
#pragma unroll
        for (int r = 0; r < 4; ++r)
            af[r] = *(const v8bf*)(Asb + (mrow + r * 16 + l16) * 32 + pch);
#pragma unroll
        for (int c = 0; c < 4; ++c)
            bfr[c] = *(const v8bf*)(Bsb + (ncol + c * 16 + l16) * 32 + pch);
        __builtin_amdgcn_s_setprio(1);
#pragma unroll
        for (int r = 0; r < 4; ++r)
#pragma unroll
            for (int c = 0; c < 4; ++c)
                acc[r][c] = __builtin_amdgcn_mfma_f32_16x16x32_bf16(
                    af[r], bfr[c], acc[r][c], 0, 0, 0);
        __builtin_amdgcn_s_setprio(0);
    };

    // prologue: 2 tiles in flight
    stage(As0, Bs0, 0);
    stage(As1, Bs1, 32);
    u16 *pa0 = As0, *pb0 = Bs0, *pa1 = As1, *pb1 = Bs1, *pa2 = As2, *pb2 = Bs2;

    for (int k0 = 0; k0 < K; k0 += 32) {
        if (k0 + 32 < K) {
            // tile t's 4 loads retired (tile t+1's 4 may remain in flight)
            asm volatile("s_waitcnt vmcnt(4)" ::: "memory");
        } else {
            asm volatile("s_waitcnt vmcnt(0)" ::: "memory");
        }
        __builtin_amdgcn_s_barrier();
        __builtin_amdgcn_sched_barrier(0);
        if (k0 + 64 < K) stage(pa2, pb2, k0 + 64);
        compute(pa0, pb0);
        u16* ta = pa0; pa0 = pa1; pa1 = pa2; pa2 = ta;
        u16* tb = pb0; pb0 = pb1; pb1 = pb2; pb2 = tb;
    }

#pragma unroll
    for (int r = 0; r < 4; ++r) {
#pragma unroll
        for (int c = 0; c < 4; ++c) {
            const int col = n0 + ncol + c * 16 + l16;
            const float bv = bias[col];
#pragma unroll
            for (int reg = 0; reg < 4; ++reg) {
                const int row = m0 + mrow + r * 16 + quad * 4 + reg;
                float val = acc[r][c][reg] + bv;
                if (MODE == 0) {
                    Cout[(size_t)row * N + col] = val;
                } else {
                    const int which = col >> 10;
                    const int rem   = col & 1023;
                    const int h     = rem >> 6;
                    const int d     = rem & 63;
                    const int b     = row >> 11;
                    const int n     = row & 2047;
                    if (which == 0) val *= KQ_SCALE;   // fold softmax scale + log2e into Q
                    u16* dst = (which == 0) ? qOut : (which == 1) ? kOut : vOut;
                    dst[(((size_t)(b * kH + h)) * kN + n) * kD + d] = f2bf(val);
                }
            }
        }
    }
}

// ------------------------------------------------- MFMA attention (bf16)
// R3/R4/R12-proven single-buffer 2-barrier body; ONLY change vs R12:
// __launch_bounds__(256, 3) instead of (256, 4).
// Occupancy ledger: dbuf(256,2)=124us @2blk/CU; singlebuf(256,2)=130us
// @2blk/CU; singlebuf(256,4)=241us — the (256,4) bound forced a 64-VGPR
// cap < the ~92 the body needs -> 534MB spill. At (256,3) the cap is
// floor(512/3)=170 >> 92, so that failure mode is impossible, while LDS
// (32KB) permits 5 blocks/CU and 92-96 VGPR permits 4-5 waves/SIMD ->
// ~4 blocks/CU resident (grid 1024 = single round) = 2x the TLP of every
// attn config measured. Counters say attn is latency-bound (MfmaUtil 26
// + VALUBusy 52, neither pipe saturated) -> TLP is the matching lever.
// Tripwires next profile: VGPR_Count ~92 (not 64), WRITE_SIZE 16MB.
__global__ __launch_bounds__(256, 3) void attn_mfma_kernel(
    const u16* __restrict__ q, const u16* __restrict__ k,
    const u16* __restrict__ v, const u32* __restrict__ mbits,
    u16* __restrict__ out)   // bf16 ao [B,N,C]
{
    __shared__ u16 Ks[128 * 64];   // 16 KB  [key][d], chunk ^= (key&7)
    __shared__ u16 Vt[64 * 128];   // 16 KB  [d][key-permuted], chunk ^= (d&15)

    const int t    = threadIdx.x;
    const int w    = t >> 6;
    const int lane = t & 63;
    const int quad = lane >> 4;
    const int l16  = lane & 15;

    const int bh    = blockIdx.x >> 4;          // 16 q-tiles of 128 rows
    const int tile0 = (blockIdx.x & 15) * 128;
    const int b     = bh >> 4;
    const int h     = bh & 15;

    const u16* qb = q + (size_t)bh * kN * kD;
    const u16* kb = k + (size_t)bh * kN * kD;
    const u16* vb = v + (size_t)bh * kN * kD;

    // Q B-fragments for 2 strips: lane holds Q[qrow][d = quad*8 + j]
    const int qrow0 = tile0 + w * 32 + l16;
    const int qrow1 = qrow0 + 16;
    v8bf qf[2][2];
    qf[0][0] = *(const v8bf*)(qb + (size_t)qrow0 * kD + quad * 8);
    qf[0][1] = *(const v8bf*)(qb + (size_t)qrow0 * kD + 32 + quad * 8);
    qf[1][0] = *(const v8bf*)(qb + (size_t)qrow1 * kD + quad * 8);
    qf[1][1] = *(const v8bf*)(qb + (size_t)qrow1 * kD + 32 + quad * 8);

    // staging geometry (constant per thread)
    // K: 2 rows x 32 dims per thread (4x 16B swizzled b128 writes)
    const int skr  = t >> 1;           // K row 0..127
    const int skh  = t & 1;            // K half (32 elems)
    // V: permuted 8 keys x 4 dims per thread -> 4x b128 transposed writes.
    const int vg   = t >> 4;           // frag chunk 0..15
    const int vdq  = t & 15;           // dim quad (dims vdq*4..+3)
    const int vrow0 = (vg >> 2) * 32 + (vg & 3) * 4;

    const u16* kp = kb + (size_t)skr * kD + skh * 32;
    const u16* vp = vb + (size_t)vrow0 * kD + vdq * 4;
    const uint4* mp0 = (const uint4*)(mbits + ((size_t)b * kN + qrow0) * 64);
    const uint4* mp1 = (const uint4*)(mbits + ((size_t)b * kN + qrow1) * 64);

    u16x8 kpre[4];
    u16x4 vpre[8];
    uint4 mpre0, mpre1;
    auto issue_prefetch = [&]() {
#pragma unroll
        for (int i = 0; i < 4; ++i)
            kpre[i] = *(const u16x8*)(kp + i * 8);
#pragma unroll
        for (int i = 0; i < 8; ++i)
            vpre[i] = *(const u16x4*)(vp + (i < 4 ? i * 64 : 1024 + (i - 4) * 64));
        mpre0 = *mp0; mpre1 = *mp1;
        kp += 128 * kD; vp += 128 * kD; ++mp0; ++mp1;
    };

    v8bf onesf;
#pragma unroll
    for (int j = 0; j < 8; ++j) onesf[j] = (__bf16)1.0f;

    v4f oacc[2][4];
    v4f rsacc[2];
#pragma unroll
    for (int qs = 0; qs < 2; ++qs) {
        rsacc[qs] = (v4f){0.f, 0.f, 0.f, 0.f};
#pragma unroll
        for (int i = 0; i < 4; ++i) oacc[qs][i] = (v4f){0.f, 0.f, 0.f, 0.f};
    }

    issue_prefetch();   // tile 0

    for (int kt = 0; kt < kN / 128; ++kt) {
        __syncthreads();   // prev tile's LDS reads done (WAR)

        // ---- stage tile kt from regs
        {
            const int cb = skh * 4;
            u16* drow = &Ks[skr * 64];
#pragma unroll
            for (int i = 0; i < 4; ++i)
                *(u16x8*)(&drow[((cb + i) ^ (skr & 7)) * 8]) = kpre[i];
        }
        {
#pragma unroll
            for (int dd = 0; dd < 4; ++dd) {
                const int d = vdq * 4 + dd;
                u16x8 col;
#pragma unroll
                for (int j = 0; j < 8; ++j) col[j] = vpre[j][dd];
                *(u16x8*)(&Vt[d * 128 + ((vg ^ (d & 15)) * 8)]) = col;
            }
        }
        const uint4 mc0 = mpre0, mc1 = mpre1;
        if (kt + 1 < kN / 128) issue_prefetch();   // regs free after ds_writes issue

        __syncthreads();   // staged tile visible

        const u32 mwa[2][4] = {{mc0.x, mc0.y, mc0.z, mc0.w},
                               {mc1.x, mc1.y, mc1.z, mc1.w}};
        v8bf pa[2][4];     // P A-fragments, built directly in registers

        // ---- S^T + softmax: lane gets s[reg] = S[key=nb*16+quad*4+reg][q=l16]
#pragma unroll
        for (int nb = 0; nb < 8; ++nb) {
            const int krow = nb * 16 + l16;
            const v8bf kf0 = *(const v8bf*)(&Ks[krow * 64 + ((quad       ^ (krow & 7)) * 8)]);
            const v8bf kf1 = *(const v8bf*)(&Ks[krow * 64 + (((quad + 4) ^ (krow & 7)) * 8)]);
#pragma unroll
            for (int qs = 0; qs < 2; ++qs) {
                v4f s = (v4f){0.f, 0.f, 0.f, 0.f};
                s = __builtin_amdgcn_mfma_f32_16x16x32_bf16(kf0, qf[qs][0], s, 0, 0, 0);
                s = __builtin_amdgcn_mfma_f32_16x16x32_bf16(kf1, qf[qs][1], s, 0, 0, 0);

                const u32 m4 = (mwa[qs][nb >> 1] >> ((nb & 1) * 16 + quad * 4)) & 0xFu;
                float e0 = fast_exp2(s[0]);
                float e1 = fast_exp2(s[1]);
                float e2 = fast_exp2(s[2]);
                float e3 = fast_exp2(s[3]);
                e0 = (m4 & 1u) ? 0.f : e0;
                e1 = (m4 & 2u) ? 0.f : e1;
                e2 = (m4 & 4u) ? 0.f : e2;
                e3 = (m4 & 8u) ? 0.f : e3;

                pa[qs][nb >> 1][(nb & 1) * 4 + 0] = (__bf16)e0;
                pa[qs][nb >> 1][(nb & 1) * 4 + 1] = (__bf16)e1;
                pa[qs][nb >> 1][(nb & 1) * 4 + 2] = (__bf16)e2;
                pa[qs][nb >> 1][(nb & 1) * 4 + 3] = (__bf16)e3;
            }
        }

        __builtin_amdgcn_s_setprio(1);
        // row-sums via ones-MFMA: rsacc row layout == oacc row layout
#pragma unroll
        for (int qs = 0; qs < 2; ++qs)
#pragma unroll
            for (int ks = 0; ks < 4; ++ks)
                rsacc[qs] = __builtin_amdgcn_mfma_f32_16x16x32_bf16(
                    pa[qs][ks], onesf, rsacc[qs], 0, 0, 0);
        // ---- PV: O[q][d] += P(32x128) @ V^T
#pragma unroll
        for (int ks = 0; ks < 4; ++ks)
#pragma unroll
            for (int db = 0; db < 4; ++db) {
                const int d = db * 16 + l16;
                const v8bf vf = *(const v8bf*)(&Vt[d * 128 + (((ks * 4 + quad) ^ (d & 15)) * 8)]);
#pragma unroll
                for (int qs = 0; qs < 2; ++qs)
                    oacc[qs][db] = __builtin_amdgcn_mfma_f32_16x16x32_bf16(
                        pa[qs][ks], vf, oacc[qs][db], 0, 0, 0);
            }
        __builtin_amdgcn_s_setprio(0);
    }

    // ---- normalize + store: rsacc rows already match oacc rows (quad*4+reg)
#pragma unroll
    for (int qs = 0; qs < 2; ++qs) {
        float inv[4];
#pragma unroll
        for (int reg = 0; reg < 4; ++reg) inv[reg] = 1.f / rsacc[qs][reg];
#pragma unroll
        for (int db = 0; db < 4; ++db)
#pragma unroll
            for (int reg = 0; reg < 4; ++reg) {
                const int row = tile0 + w * 32 + qs * 16 + quad * 4 + reg;
                const int col = h * 64 + db * 16 + l16;
                out[((size_t)(b * kN + row)) * kC + col] = f2bf(oacc[qs][db][reg] * inv[reg]);
            }
    }
}

// ------------------------------------------------------------------ launch
extern "C" void kernel_launch(void* const* d_in, const int* in_sizes, int n_in,
                              void* d_out, int out_size, void* d_ws, size_t ws_size,
                              hipStream_t stream)
{
    const float* x     = (const float*)d_in[0];
    const int*   mask  = (const int*)d_in[1];
    const float* Wqkv  = (const float*)d_in[2];
    const float* bqkv  = (const float*)d_in[3];
    const float* Wproj = (const float*)d_in[4];
    const float* bproj = (const float*)d_in[5];
    float* out = (float*)d_out;

    const size_t nx = (size_t)kB * kN * kC;
    const size_t qkv_elems = (size_t)kB * kH * kN * kD;
    u16* xb     = (u16*)d_ws;
    u16* qbuf   = xb + nx;
    u16* kbuf   = qbuf + qkv_elems;
    u16* vbuf   = kbuf + qkv_elems;
    u16* aob    = vbuf + qkv_elems;
    u16* Wqkvt  = aob + nx;
    u16* Wprojt = Wqkvt + (size_t)3 * kC * kC;
    u32* mbits  = (u32*)(Wprojt + (size_t)kC * kC);   // 2 MB bitmask

    maskpack_kernel<<<dim3(2048), dim3(256), 0, stream>>>(mask, mbits);
    cast_bf16_kernel<<<dim3(nx / 1024), dim3(256), 0, stream>>>(x, xb);
    tpose_cast_kernel<<<dim3(3 * kC / 64, kC / 64), dim3(256), 0, stream>>>(
        Wqkv, Wqkvt, kC, 3 * kC);
    tpose_cast_kernel<<<dim3(kC / 64, kC / 64), dim3(256), 0, stream>>>(
        Wproj, Wprojt, kC, kC);

    // 1-D grids (XCD swizzle inside): nwg = (N/128)*(M/128), % 8 == 0
    gemm_mfma_kernel<1><<<dim3((3 * kC / 128) * (kB * kN / 128)), dim3(256), 0, stream>>>(
        xb, Wqkvt, bqkv, nullptr, qbuf, kbuf, vbuf, kB * kN, 3 * kC, kC);

    attn_mfma_kernel<<<dim3(kB * kH * (kN / 128)), dim3(256), 0, stream>>>(
        qbuf, kbuf, vbuf, mbits, aob);

    gemm_mfma_kernel<0><<<dim3((kC / 128) * (kB * kN / 128)), dim3(256), 0, stream>>>(
        aob, Wprojt, bproj, out, nullptr, nullptr, nullptr, kB * kN, kC, kC);
}

// Round 16
// 358.909 us; speedup vs baseline: 1.3757x; 1.0199x over previous
//
#include <hip/hip_runtime.h>
#include <cstdint>
#include <cstddef>

constexpr int kC = 1024;   // DIM
constexpr int kH = 16;     // heads
constexpr int kB = 4;      // batch
constexpr int kN = 2048;   // seq
constexpr int kD = 64;     // head dim

// softmax scale folded into Q at the QKV-GEMM epilogue: 0.125 * log2(e)
#define KQ_SCALE 0.18033688011112042f

typedef unsigned short u16;
typedef unsigned int   u32;
typedef unsigned long long u64;
typedef __bf16 v8bf  __attribute__((ext_vector_type(8)));
typedef float  v4f   __attribute__((ext_vector_type(4)));
typedef u16    u16x8 __attribute__((ext_vector_type(8)));
typedef u16    u16x4 __attribute__((ext_vector_type(4)));

__device__ inline u16 f2bf(float f) {
    union { float f; unsigned u; } v; v.f = f;
    unsigned r = v.u + 0x7FFFu + ((v.u >> 16) & 1u);   // RNE
    return (u16)(r >> 16);
}

__device__ inline float fast_exp2(float x) {
#if __has_builtin(__builtin_amdgcn_exp2f)
    return __builtin_amdgcn_exp2f(x);          // bare v_exp_f32
#else
    return __expf(x * 0.6931471805599453f);
#endif
}

// async 16B global -> LDS (wave-uniform LDS base + lane*16)
__device__ inline void gl2lds16(const u16* g, u16* l) {
    __builtin_amdgcn_global_load_lds(
        (const __attribute__((address_space(1))) void*)g,
        (__attribute__((address_space(3))) void*)l, 16, 0, 0);
}

// --------------------------------------------------------- fused prep
// maskpack + x-cast + 2x weight-transpose were 4 independent dispatches
// (~25-45 us incl. 3 inter-dispatch gaps); all bodies are the proven R15
// versions, index-remapped onto one grid:
//   [0, 8192)        cast_bf16 (x fp32 -> bf16)
//   [8192, 10240)    maskpack  (grid-strided, stride 2048*4 segments)
//   [10240, 11008)   tpose Wqkv  (48 x 16 tiles)
//   [11008, 11264)   tpose Wproj (16 x 16 tiles)
constexpr int kPrepCast  = 8192;
constexpr int kPrepMask  = 2048;
constexpr int kPrepTpA   = 768;    // (3*kC/64) * (kC/64) = 48*16
constexpr int kPrepTpB   = 256;    // (kC/64) * (kC/64)  = 16*16
constexpr int kPrepBlocks = kPrepCast + kPrepMask + kPrepTpA + kPrepTpB;

__device__ inline void tpose_body(const float* __restrict__ W,
                                  u16* __restrict__ Wt, int R, int Cc,
                                  int bx, int by, int t, u16 (*tile)[65])
{
    const int c0 = bx * 64;
    const int r0 = by * 64;
#pragma unroll
    for (int it = 0; it < 16; ++it) {
        const int r = it * 4 + (t >> 6);
        const int c = t & 63;
        tile[c][r] = f2bf(W[(size_t)(r0 + r) * Cc + c0 + c]);
    }
    __syncthreads();
#pragma unroll
    for (int it = 0; it < 16; ++it) {
        const int rr = it * 4 + (t >> 6);
        const int cc = t & 63;
        Wt[(size_t)(c0 + rr) * R + r0 + cc] = tile[rr][cc];
    }
}

__global__ __launch_bounds__(256) void prep_kernel(
    const float* __restrict__ x,    u16* __restrict__ xb,
    const int*   __restrict__ mask, u32* __restrict__ bits,
    const float* __restrict__ Wqkv, u16* __restrict__ Wqkvt,
    const float* __restrict__ Wproj,u16* __restrict__ Wprojt)
{
    __shared__ u16 tile[64][65];
    const int bid = (int)blockIdx.x;
    const int t   = threadIdx.x;

    if (bid < kPrepCast) {
        // ---- cast x -> bf16 (proven cast_bf16 body)
        const int i = bid * 256 + t;
        const float4 f = ((const float4*)x)[i];
        u16x4 o;
        o.x = f2bf(f.x); o.y = f2bf(f.y); o.z = f2bf(f.z); o.w = f2bf(f.w);
        ((u16x4*)xb)[i] = o;
    } else if (bid < kPrepCast + kPrepMask) {
        // ---- maskpack (proven body; stride = kPrepMask*4 segments)
        const int blk  = bid - kPrepCast;
        const int lane = t & 63;
        const int wv   = t >> 6;
        const int nseg = kB * kN * 32;
        for (int seg = blk * 4 + wv; seg < nseg; seg += kPrepMask * 4) {
            const size_t row = (size_t)(seg >> 5);   // b*N + q
            const int s = seg & 31;                  // 64-key segment
            const int m = mask[row * kN + s * 64 + lane];
            const u64 bal = __ballot(m != 0);
            if (lane == 0) ((u64*)bits)[row * 32 + s] = bal;
        }
    } else if (bid < kPrepCast + kPrepMask + kPrepTpA) {
        // ---- transpose Wqkv [kC][3kC] -> Wqkvt [3kC][kC]
        const int b1 = bid - (kPrepCast + kPrepMask);
        tpose_body(Wqkv, Wqkvt, kC, 3 * kC, b1 % 48, b1 / 48, t, tile);
    } else {
        // ---- transpose Wproj [kC][kC] -> Wprojt [kC][kC]
        const int b2 = bid - (kPrepCast + kPrepMask + kPrepTpA);
        tpose_body(Wproj, Wprojt, kC, kC, b2 % 16, b2 / 16, t, tile);
    }
}

// ---------------------------------------------------- bf16 MFMA GEMM
// C[M,N] = A[M,K] @ Bt[N,K]^T + bias.  128x128 tile, BK=32, 4 waves.
// 3-buffer / 2-ahead pipeline with COUNTED vmcnt + raw s_barrier (T3/T4).
// R5/R10/R13/R15-proven config — unchanged.
template <int MODE>
__global__ __launch_bounds__(256, 3) void gemm_mfma_kernel(
    const u16* __restrict__ A, const u16* __restrict__ Bt,
    const float* __restrict__ bias, float* __restrict__ Cout,
    u16* __restrict__ qOut, u16* __restrict__ kOut, u16* __restrict__ vOut,
    int M, int N, int K)
{
    __shared__ u16 As0[128 * 32], Bs0[128 * 32];
    __shared__ u16 As1[128 * 32], Bs1[128 * 32];
    __shared__ u16 As2[128 * 32], Bs2[128 * 32];
    const int t    = threadIdx.x;
    const int w    = t >> 6;
    const int lane = t & 63;
    const int quad = lane >> 4;
    const int l16  = lane & 15;

    // XCD-chunked bijective swizzle (nwg % 8 == 0), column-major walk
    const int nby = M >> 7;
    const int q8  = (int)gridDim.x >> 3;
    const int bid = (int)blockIdx.x;
    const int swz = (bid & 7) * q8 + (bid >> 3);
    const int m0  = (swz % nby) * 128;
    const int n0  = (swz / nby) * 128;

    const int sr  = lane >> 2;                              // staging row in 16
    const int scs = ((lane & 3) ^ ((sr >> 1) & 3)) * 8;     // swizzled src chunk
    const u16* Ag0 = A  + (size_t)(m0 + 32 * w      + sr) * K + scs;
    const u16* Ag1 = A  + (size_t)(m0 + 32 * w + 16 + sr) * K + scs;
    const u16* Bg0 = Bt + (size_t)(n0 + 32 * w      + sr) * K + scs;
    const u16* Bg1 = Bt + (size_t)(n0 + 32 * w + 16 + sr) * K + scs;

    v4f acc[4][4];
#pragma unroll
    for (int r = 0; r < 4; ++r)
#pragma unroll
        for (int c = 0; c < 4; ++c) acc[r][c] = (v4f){0.f, 0.f, 0.f, 0.f};

    const int mrow = (w >> 1) * 64;
    const int ncol = (w & 1) * 64;
    const int pch  = (quad ^ ((l16 >> 1) & 3)) * 8;         // swizzled read chunk

    auto stage = [&](u16* Asb, u16* Bsb, int k0) {
        gl2lds16(Ag0 + k0, Asb + (32 * w) * 32);
        gl2lds16(Ag1 + k0, Asb + (32 * w + 16) * 32);
        gl2lds16(Bg0 + k0, Bsb + (32 * w) * 32);
        gl2lds16(Bg1 + k0, Bsb + (32 * w + 16) * 32);
    };
    auto compute = [&](const u16* Asb, const u16* Bsb) {
        v8bf af[4], bfr[4];
#pragma unroll
        for (int r = 0; r < 4; ++r)
            af[r] = *(const v8bf*)(Asb + (mrow + r * 16 + l16) * 32 + pch);
#pragma unroll
        for (int c = 0; c < 4; ++c)
            bfr[c] = *(const v8bf*)(Bsb + (ncol + c * 16 + l16) * 32 + pch);
        __builtin_amdgcn_s_setprio(1);
#pragma unroll
        for (int r = 0; r < 4; ++r)
#pragma unroll
            for (int c = 0; c < 4; ++c)
                acc[r][c] = __builtin_amdgcn_mfma_f32_16x16x32_bf16(
                    af[r], bfr[c], acc[r][c], 0, 0, 0);
        __builtin_amdgcn_s_setprio(0);
    };

    // prologue: 2 tiles in flight
    stage(As0, Bs0, 0);
    stage(As1, Bs1, 32);
    u16 *pa0 = As0, *pb0 = Bs0, *pa1 = As1, *pb1 = Bs1, *pa2 = As2, *pb2 = Bs2;

    for (int k0 = 0; k0 < K; k0 += 32) {
        if (k0 + 32 < K) {
            // tile t's 4 loads retired (tile t+1's 4 may remain in flight)
            asm volatile("s_waitcnt vmcnt(4)" ::: "memory");
        } else {
            asm volatile("s_waitcnt vmcnt(0)" ::: "memory");
        }
        __builtin_amdgcn_s_barrier();
        __builtin_amdgcn_sched_barrier(0);
        if (k0 + 64 < K) stage(pa2, pb2, k0 + 64);
        compute(pa0, pb0);
        u16* ta = pa0; pa0 = pa1; pa1 = pa2; pa2 = ta;
        u16* tb = pb0; pb0 = pb1; pb1 = pb2; pb2 = tb;
    }

#pragma unroll
    for (int r = 0; r < 4; ++r) {
#pragma unroll
        for (int c = 0; c < 4; ++c) {
            const int col = n0 + ncol + c * 16 + l16;
            const float bv = bias[col];
#pragma unroll
            for (int reg = 0; reg < 4; ++reg) {
                const int row = m0 + mrow + r * 16 + quad * 4 + reg;
                float val = acc[r][c][reg] + bv;
                if (MODE == 0) {
                    Cout[(size_t)row * N + col] = val;
                } else {
                    const int which = col >> 10;
                    const int rem   = col & 1023;
                    const int h     = rem >> 6;
                    const int d     = rem & 63;
                    const int b     = row >> 11;
                    const int n     = row & 2047;
                    if (which == 0) val *= KQ_SCALE;   // fold softmax scale + log2e into Q
                    u16* dst = (which == 0) ? qOut : (which == 1) ? kOut : vOut;
                    dst[(((size_t)(b * kH + h)) * kN + n) * kD + d] = f2bf(val);
                }
            }
        }
    }
}

// ------------------------------------------------- MFMA attention (bf16)
// R15-proven version, byte-for-byte (best measured: 123.4 us). Single-
// buffer 2-barrier loop, __launch_bounds__(256,3), VGPR 84, occupancy 26%.
// Issue-bound: occupancy 19->26% moved duration 0 (R15); barrier halving
// moved 0 (R3 vs R5); PV pipelining moved 0 (R14); geometry up spilled
// (R11/R12). This config ties the dbuf best with lower LDS.
__global__ __launch_bounds__(256, 3) void attn_mfma_kernel(
    const u16* __restrict__ q, const u16* __restrict__ k,
    const u16* __restrict__ v, const u32* __restrict__ mbits,
    u16* __restrict__ out)   // bf16 ao [B,N,C]
{
    __shared__ u16 Ks[128 * 64];   // 16 KB  [key][d], chunk ^= (key&7)
    __shared__ u16 Vt[64 * 128];   // 16 KB  [d][key-permuted], chunk ^= (d&15)

    const int t    = threadIdx.x;
    const int w    = t >> 6;
    const int lane = t & 63;
    const int quad = lane >> 4;
    const int l16  = lane & 15;

    const int bh    = blockIdx.x >> 4;          // 16 q-tiles of 128 rows
    const int tile0 = (blockIdx.x & 15) * 128;
    const int b     = bh >> 4;
    const int h     = bh & 15;

    const u16* qb = q + (size_t)bh * kN * kD;
    const u16* kb = k + (size_t)bh * kN * kD;
    const u16* vb = v + (size_t)bh * kN * kD;

    // Q B-fragments for 2 strips: lane holds Q[qrow][d = quad*8 + j]
    const int qrow0 = tile0 + w * 32 + l16;
    const int qrow1 = qrow0 + 16;
    v8bf qf[2][2];
    qf[0][0] = *(const v8bf*)(qb + (size_t)qrow0 * kD + quad * 8);
    qf[0][1] = *(const v8bf*)(qb + (size_t)qrow0 * kD + 32 + quad * 8);
    qf[1][0] = *(const v8bf*)(qb + (size_t)qrow1 * kD + quad * 8);
    qf[1][1] = *(const v8bf*)(qb + (size_t)qrow1 * kD + 32 + quad * 8);

    // staging geometry (constant per thread)
    // K: 2 rows x 32 dims per thread (4x 16B swizzled b128 writes)
    const int skr  = t >> 1;           // K row 0..127
    const int skh  = t & 1;            // K half (32 elems)
    // V: permuted 8 keys x 4 dims per thread -> 4x b128 transposed writes.
    const int vg   = t >> 4;           // frag chunk 0..15
    const int vdq  = t & 15;           // dim quad (dims vdq*4..+3)
    const int vrow0 = (vg >> 2) * 32 + (vg & 3) * 4;

    const u16* kp = kb + (size_t)skr * kD + skh * 32;
    const u16* vp = vb + (size_t)vrow0 * kD + vdq * 4;
    const uint4* mp0 = (const uint4*)(mbits + ((size_t)b * kN + qrow0) * 64);
    const uint4* mp1 = (const uint4*)(mbits + ((size_t)b * kN + qrow1) * 64);

    u16x8 kpre[4];
    u16x4 vpre[8];
    uint4 mpre0, mpre1;
    auto issue_prefetch = [&]() {
#pragma unroll
        for (int i = 0; i < 4; ++i)
            kpre[i] = *(const u16x8*)(kp + i * 8);
#pragma unroll
        for (int i = 0; i < 8; ++i)
            vpre[i] = *(const u16x4*)(vp + (i < 4 ? i * 64 : 1024 + (i - 4) * 64));
        mpre0 = *mp0; mpre1 = *mp1;
        kp += 128 * kD; vp += 128 * kD; ++mp0; ++mp1;
    };

    v8bf onesf;
#pragma unroll
    for (int j = 0; j < 8; ++j) onesf[j] = (__bf16)1.0f;

    v4f oacc[2][4];
    v4f rsacc[2];
#pragma unroll
    for (int qs = 0; qs < 2; ++qs) {
        rsacc[qs] = (v4f){0.f, 0.f, 0.f, 0.f};
#pragma unroll
        for (int i = 0; i < 4; ++i) oacc[qs][i] = (v4f){0.f, 0.f, 0.f, 0.f};
    }

    issue_prefetch();   // tile 0

    for (int kt = 0; kt < kN / 128; ++kt) {
        __syncthreads();   // prev tile's LDS reads done (WAR)

        // ---- stage tile kt from regs
        {
            const int cb = skh * 4;
            u16* drow = &Ks[skr * 64];
#pragma unroll
            for (int i = 0; i < 4; ++i)
                *(u16x8*)(&drow[((cb + i) ^ (skr & 7)) * 8]) = kpre[i];
        }
        {
#pragma unroll
            for (int dd = 0; dd < 4; ++dd) {
                const int d = vdq * 4 + dd;
                u16x8 col;
#pragma unroll
                for (int j = 0; j < 8; ++j) col[j] = vpre[j][dd];
                *(u16x8*)(&Vt[d * 128 + ((vg ^ (d & 15)) * 8)]) = col;
            }
        }
        const uint4 mc0 = mpre0, mc1 = mpre1;
        if (kt + 1 < kN / 128) issue_prefetch();   // regs free after ds_writes issue

        __syncthreads();   // staged tile visible

        const u32 mwa[2][4] = {{mc0.x, mc0.y, mc0.z, mc0.w},
                               {mc1.x, mc1.y, mc1.z, mc1.w}};
        v8bf pa[2][4];     // P A-fragments, built directly in registers

        // ---- S^T + softmax: lane gets s[reg] = S[key=nb*16+quad*4+reg][q=l16]
#pragma unroll
        for (int nb = 0; nb < 8; ++nb) {
            const int krow = nb * 16 + l16;
            const v8bf kf0 = *(const v8bf*)(&Ks[krow * 64 + ((quad       ^ (krow & 7)) * 8)]);
            const v8bf kf1 = *(const v8bf*)(&Ks[krow * 64 + (((quad + 4) ^ (krow & 7)) * 8)]);
#pragma unroll
            for (int qs = 0; qs < 2; ++qs) {
                v4f s = (v4f){0.f, 0.f, 0.f, 0.f};
                s = __builtin_amdgcn_mfma_f32_16x16x32_bf16(kf0, qf[qs][0], s, 0, 0, 0);
                s = __builtin_amdgcn_mfma_f32_16x16x32_bf16(kf1, qf[qs][1], s, 0, 0, 0);

                const u32 m4 = (mwa[qs][nb >> 1] >> ((nb & 1) * 16 + quad * 4)) & 0xFu;
                float e0 = fast_exp2(s[0]);
                float e1 = fast_exp2(s[1]);
                float e2 = fast_exp2(s[2]);
                float e3 = fast_exp2(s[3]);
                e0 = (m4 & 1u) ? 0.f : e0;
                e1 = (m4 & 2u) ? 0.f : e1;
                e2 = (m4 & 4u) ? 0.f : e2;
                e3 = (m4 & 8u) ? 0.f : e3;

                pa[qs][nb >> 1][(nb & 1) * 4 + 0] = (__bf16)e0;
                pa[qs][nb >> 1][(nb & 1) * 4 + 1] = (__bf16)e1;
                pa[qs][nb >> 1][(nb & 1) * 4 + 2] = (__bf16)e2;
                pa[qs][nb >> 1][(nb & 1) * 4 + 3] = (__bf16)e3;
            }
        }

        __builtin_amdgcn_s_setprio(1);
        // row-sums via ones-MFMA: rsacc row layout == oacc row layout
#pragma unroll
        for (int qs = 0; qs < 2; ++qs)
#pragma unroll
            for (int ks = 0; ks < 4; ++ks)
                rsacc[qs] = __builtin_amdgcn_mfma_f32_16x16x32_bf16(
                    pa[qs][ks], onesf, rsacc[qs], 0, 0, 0);
        // ---- PV: O[q][d] += P(32x128) @ V^T
#pragma unroll
        for (int ks = 0; ks < 4; ++ks)
#pragma unroll
            for (int db = 0; db < 4; ++db) {
                const int d = db * 16 + l16;
                const v8bf vf = *(const v8bf*)(&Vt[d * 128 + (((ks * 4 + quad) ^ (d & 15)) * 8)]);
#pragma unroll
                for (int qs = 0; qs < 2; ++qs)
                    oacc[qs][db] = __builtin_amdgcn_mfma_f32_16x16x32_bf16(
                        pa[qs][ks], vf, oacc[qs][db], 0, 0, 0);
            }
        __builtin_amdgcn_s_setprio(0);
    }

    // ---- normalize + store: rsacc rows already match oacc rows (quad*4+reg)
#pragma unroll
    for (int qs = 0; qs < 2; ++qs) {
        float inv[4];
#pragma unroll
        for (int reg = 0; reg < 4; ++reg) inv[reg] = 1.f / rsacc[qs][reg];
#pragma unroll
        for (int db = 0; db < 4; ++db)
#pragma unroll
            for (int reg = 0; reg < 4; ++reg) {
                const int row = tile0 + w * 32 + qs * 16 + quad * 4 + reg;
                const int col = h * 64 + db * 16 + l16;
                out[((size_t)(b * kN + row)) * kC + col] = f2bf(oacc[qs][db][reg] * inv[reg]);
            }
    }
}

// ------------------------------------------------------------------ launch
extern "C" void kernel_launch(void* const* d_in, const int* in_sizes, int n_in,
                              void* d_out, int out_size, void* d_ws, size_t ws_size,
                              hipStream_t stream)
{
    const float* x     = (const float*)d_in[0];
    const int*   mask  = (const int*)d_in[1];
    const float* Wqkv  = (const float*)d_in[2];
    const float* bqkv  = (const float*)d_in[3];
    const float* Wproj = (const float*)d_in[4];
    const float* bproj = (const float*)d_in[5];
    float* out = (float*)d_out;

    const size_t nx = (size_t)kB * kN * kC;
    const size_t qkv_elems = (size_t)kB * kH * kN * kD;
    u16* xb     = (u16*)d_ws;
    u16* qbuf   = xb + nx;
    u16* kbuf   = qbuf + qkv_elems;
    u16* vbuf   = kbuf + qkv_elems;
    u16* aob    = vbuf + qkv_elems;
    u16* Wqkvt  = aob + nx;
    u16* Wprojt = Wqkvt + (size_t)3 * kC * kC;
    u32* mbits  = (u32*)(Wprojt + (size_t)kC * kC);   // 2 MB bitmask

    // fused prep: cast + maskpack + both weight transposes, one dispatch
    prep_kernel<<<dim3(kPrepBlocks), dim3(256), 0, stream>>>(
        x, xb, mask, mbits, Wqkv, Wqkvt, Wproj, Wprojt);

    // 1-D grids (XCD swizzle inside): nwg = (N/128)*(M/128), % 8 == 0
    gemm_mfma_kernel<1><<<dim3((3 * kC / 128) * (kB * kN / 128)), dim3(256), 0, stream>>>(
        xb, Wqkvt, bqkv, nullptr, qbuf, kbuf, vbuf, kB * kN, 3 * kC, kC);

    attn_mfma_kernel<<<dim3(kB * kH * (kN / 128)), dim3(256), 0, stream>>>(
        qbuf, kbuf, vbuf, mbits, aob);

    gemm_mfma_kernel<0><<<dim3((kC / 128) * (kB * kN / 128)), dim3(256), 0, stream>>>(
        aob, Wprojt, bproj, out, nullptr, nullptr, nullptr, kB * kN, kC, kC);
}

// Round 17
// 356.291 us; speedup vs baseline: 1.3858x; 1.0073x over previous
//
#include <hip/hip_runtime.h>
#include <cstdint>
#include <cstddef>

constexpr int kC = 1024;   // DIM
constexpr int kH = 16;     // heads
constexpr int kB = 4;      // batch
constexpr int kN = 2048;   // seq
constexpr int kD = 64;     // head dim

// softmax scale folded into Q at the QKV-GEMM epilogue: 0.125 * log2(e)
#define KQ_SCALE 0.18033688011112042f

typedef unsigned short u16;
typedef unsigned int   u32;
typedef unsigned long long u64;
typedef __bf16 v8bf  __attribute__((ext_vector_type(8)));
typedef float  v4f   __attribute__((ext_vector_type(4)));
typedef u16    u16x8 __attribute__((ext_vector_type(8)));
typedef u16    u16x4 __attribute__((ext_vector_type(4)));

__device__ inline u16 f2bf(float f) {
    union { float f; unsigned u; } v; v.f = f;
    unsigned r = v.u + 0x7FFFu + ((v.u >> 16) & 1u);   // RNE
    return (u16)(r >> 16);
}

__device__ inline float fast_exp2(float x) {
#if __has_builtin(__builtin_amdgcn_exp2f)
    return __builtin_amdgcn_exp2f(x);          // bare v_exp_f32
#else
    return __expf(x * 0.6931471805599453f);
#endif
}

// async 16B global -> LDS (wave-uniform LDS base + lane*16)
__device__ inline void gl2lds16(const u16* g, u16* l) {
    __builtin_amdgcn_global_load_lds(
        (const __attribute__((address_space(1))) void*)g,
        (__attribute__((address_space(3))) void*)l, 16, 0, 0);
}

// --------------------------------------------------------- fused prep
// maskpack + x-cast + 2x weight-transpose in one dispatch (R16-proven,
// -7 us vs 4 dispatches). Bodies are the proven R15 versions,
// index-remapped onto one grid:
//   [0, 8192)        cast_bf16 (x fp32 -> bf16)
//   [8192, 10240)    maskpack  (grid-strided, stride 2048*4 segments)
//   [10240, 11008)   tpose Wqkv  (48 x 16 tiles)
//   [11008, 11264)   tpose Wproj (16 x 16 tiles)
constexpr int kPrepCast  = 8192;
constexpr int kPrepMask  = 2048;
constexpr int kPrepTpA   = 768;    // (3*kC/64) * (kC/64) = 48*16
constexpr int kPrepTpB   = 256;    // (kC/64) * (kC/64)  = 16*16
constexpr int kPrepBlocks = kPrepCast + kPrepMask + kPrepTpA + kPrepTpB;

__device__ inline void tpose_body(const float* __restrict__ W,
                                  u16* __restrict__ Wt, int R, int Cc,
                                  int bx, int by, int t, u16 (*tile)[65])
{
    const int c0 = bx * 64;
    const int r0 = by * 64;
#pragma unroll
    for (int it = 0; it < 16; ++it) {
        const int r = it * 4 + (t >> 6);
        const int c = t & 63;
        tile[c][r] = f2bf(W[(size_t)(r0 + r) * Cc + c0 + c]);
    }
    __syncthreads();
#pragma unroll
    for (int it = 0; it < 16; ++it) {
        const int rr = it * 4 + (t >> 6);
        const int cc = t & 63;
        Wt[(size_t)(c0 + rr) * R + r0 + cc] = tile[rr][cc];
    }
}

__global__ __launch_bounds__(256) void prep_kernel(
    const float* __restrict__ x,    u16* __restrict__ xb,
    const int*   __restrict__ mask, u32* __restrict__ bits,
    const float* __restrict__ Wqkv, u16* __restrict__ Wqkvt,
    const float* __restrict__ Wproj,u16* __restrict__ Wprojt)
{
    __shared__ u16 tile[64][65];
    const int bid = (int)blockIdx.x;
    const int t   = threadIdx.x;

    if (bid < kPrepCast) {
        // ---- cast x -> bf16 (proven cast_bf16 body)
        const int i = bid * 256 + t;
        const float4 f = ((const float4*)x)[i];
        u16x4 o;
        o.x = f2bf(f.x); o.y = f2bf(f.y); o.z = f2bf(f.z); o.w = f2bf(f.w);
        ((u16x4*)xb)[i] = o;
    } else if (bid < kPrepCast + kPrepMask) {
        // ---- maskpack (proven body; stride = kPrepMask*4 segments)
        const int blk  = bid - kPrepCast;
        const int lane = t & 63;
        const int wv   = t >> 6;
        const int nseg = kB * kN * 32;
        for (int seg = blk * 4 + wv; seg < nseg; seg += kPrepMask * 4) {
            const size_t row = (size_t)(seg >> 5);   // b*N + q
            const int s = seg & 31;                  // 64-key segment
            const int m = mask[row * kN + s * 64 + lane];
            const u64 bal = __ballot(m != 0);
            if (lane == 0) ((u64*)bits)[row * 32 + s] = bal;
        }
    } else if (bid < kPrepCast + kPrepMask + kPrepTpA) {
        // ---- transpose Wqkv [kC][3kC] -> Wqkvt [3kC][kC]
        const int b1 = bid - (kPrepCast + kPrepMask);
        tpose_body(Wqkv, Wqkvt, kC, 3 * kC, b1 % 48, b1 / 48, t, tile);
    } else {
        // ---- transpose Wproj [kC][kC] -> Wprojt [kC][kC]
        const int b2 = bid - (kPrepCast + kPrepMask + kPrepTpA);
        tpose_body(Wproj, Wprojt, kC, kC, b2 % 16, b2 / 16, t, tile);
    }
}

// ---------------------------------------------------- bf16 MFMA GEMM
// C[M,N] = A[M,K] @ Bt[N,K]^T + bias.  128x128 tile, BK=32, 4 waves.
// 3-buffer / 2-ahead pipeline with COUNTED vmcnt + raw s_barrier (T3/T4).
// R5/R10/R13/R15/R16-proven config — unchanged.
template <int MODE>
__global__ __launch_bounds__(256, 3) void gemm_mfma_kernel(
    const u16* __restrict__ A, const u16* __restrict__ Bt,
    const float* __restrict__ bias, float* __restrict__ Cout,
    u16* __restrict__ qOut, u16* __restrict__ kOut, u16* __restrict__ vOut,
    int M, int N, int K)
{
    __shared__ u16 As0[128 * 32], Bs0[128 * 32];
    __shared__ u16 As1[128 * 32], Bs1[128 * 32];
    __shared__ u16 As2[128 * 32], Bs2[128 * 32];
    const int t    = threadIdx.x;
    const int w    = t >> 6;
    const int lane = t & 63;
    const int quad = lane >> 4;
    const int l16  = lane & 15;

    // XCD-chunked bijective swizzle (nwg % 8 == 0), column-major walk
    const int nby = M >> 7;
    const int q8  = (int)gridDim.x >> 3;
    const int bid = (int)blockIdx.x;
    const int swz = (bid & 7) * q8 + (bid >> 3);
    const int m0  = (swz % nby) * 128;
    const int n0  = (swz / nby) * 128;

    const int sr  = lane >> 2;                              // staging row in 16
    const int scs = ((lane & 3) ^ ((sr >> 1) & 3)) * 8;     // swizzled src chunk
    const u16* Ag0 = A  + (size_t)(m0 + 32 * w      + sr) * K + scs;
    const u16* Ag1 = A  + (size_t)(m0 + 32 * w + 16 + sr) * K + scs;
    const u16* Bg0 = Bt + (size_t)(n0 + 32 * w      + sr) * K + scs;
    const u16* Bg1 = Bt + (size_t)(n0 + 32 * w + 16 + sr) * K + scs;

    v4f acc[4][4];
#pragma unroll
    for (int r = 0; r < 4; ++r)
#pragma unroll
        for (int c = 0; c < 4; ++c) acc[r][c] = (v4f){0.f, 0.f, 0.f, 0.f};

    const int mrow = (w >> 1) * 64;
    const int ncol = (w & 1) * 64;
    const int pch  = (quad ^ ((l16 >> 1) & 3)) * 8;         // swizzled read chunk

    auto stage = [&](u16* Asb, u16* Bsb, int k0) {
        gl2lds16(Ag0 + k0, Asb + (32 * w) * 32);
        gl2lds16(Ag1 + k0, Asb + (32 * w + 16) * 32);
        gl2lds16(Bg0 + k0, Bsb + (32 * w) * 32);
        gl2lds16(Bg1 + k0, Bsb + (32 * w + 16) * 32);
    };
    auto compute = [&](const u16* Asb, const u16* Bsb) {
        v8bf af[4], bfr[4];
#pragma unroll
        for (int r = 0; r < 4; ++r)
            af[r] = *(const v8bf*)(Asb + (mrow + r * 16 + l16) * 32 + pch);
#pragma unroll
        for (int c = 0; c < 4; ++c)
            bfr[c] = *(const v8bf*)(Bsb + (ncol + c * 16 + l16) * 32 + pch);
        __builtin_amdgcn_s_setprio(1);
#pragma unroll
        for (int r = 0; r < 4; ++r)
#pragma unroll
            for (int c = 0; c < 4; ++c)
                acc[r][c] = __builtin_amdgcn_mfma_f32_16x16x32_bf16(
                    af[r], bfr[c], acc[r][c], 0, 0, 0);
        __builtin_amdgcn_s_setprio(0);
    };

    // prologue: 2 tiles in flight
    stage(As0, Bs0, 0);
    stage(As1, Bs1, 32);
    u16 *pa0 = As0, *pb0 = Bs0, *pa1 = As1, *pb1 = Bs1, *pa2 = As2, *pb2 = Bs2;

    for (int k0 = 0; k0 < K; k0 += 32) {
        if (k0 + 32 < K) {
            // tile t's 4 loads retired (tile t+1's 4 may remain in flight)
            asm volatile("s_waitcnt vmcnt(4)" ::: "memory");
        } else {
            asm volatile("s_waitcnt vmcnt(0)" ::: "memory");
        }
        __builtin_amdgcn_s_barrier();
        __builtin_amdgcn_sched_barrier(0);
        if (k0 + 64 < K) stage(pa2, pb2, k0 + 64);
        compute(pa0, pb0);
        u16* ta = pa0; pa0 = pa1; pa1 = pa2; pa2 = ta;
        u16* tb = pb0; pb0 = pb1; pb1 = pb2; pb2 = tb;
    }

#pragma unroll
    for (int r = 0; r < 4; ++r) {
#pragma unroll
        for (int c = 0; c < 4; ++c) {
            const int col = n0 + ncol + c * 16 + l16;
            const float bv = bias[col];
#pragma unroll
            for (int reg = 0; reg < 4; ++reg) {
                const int row = m0 + mrow + r * 16 + quad * 4 + reg;
                float val = acc[r][c][reg] + bv;
                if (MODE == 0) {
                    Cout[(size_t)row * N + col] = val;
                } else {
                    const int which = col >> 10;
                    const int rem   = col & 1023;
                    const int h     = rem >> 6;
                    const int d     = rem & 63;
                    const int b     = row >> 11;
                    const int n     = row & 2047;
                    if (which == 0) val *= KQ_SCALE;   // fold softmax scale + log2e into Q
                    u16* dst = (which == 0) ? qOut : (which == 1) ? kOut : vOut;
                    dst[(((size_t)(b * kH + h)) * kN + n) * kD + d] = f2bf(val);
                }
            }
        }
    }
}

// ------------------------------------------------- MFMA attention (bf16)
// R15/R16-proven version (best measured: 123.4-124.5 us). Single-buffer
// 2-barrier loop, __launch_bounds__(256,3), VGPR 84, occupancy 26%.
// Issue-bound: occupancy 19->26% moved duration 0 (R15); barrier halving
// moved 0 (R3 vs R5); PV pipelining moved 0 (R14); geometry up spilled
// (R11/R12). This config ties the dbuf best with lower LDS.
__global__ __launch_bounds__(256, 3) void attn_mfma_kernel(
    const u16* __restrict__ q, const u16* __restrict__ k,
    const u16* __restrict__ v, const u32* __restrict__ mbits,
    u16* __restrict__ out)   // bf16 ao [B,N,C]
{
    __shared__ u16 Ks[128 * 64];   // 16 KB  [key][d], chunk ^= (key&7)
    __shared__ u16 Vt[64 * 128];   // 16 KB  [d][key-permuted], chunk ^= (d&15)

    const int t    = threadIdx.x;
    const int w    = t >> 6;
    const int lane = t & 63;
    const int quad = lane >> 4;
    const int l16  = lane & 15;

    const int bh    = blockIdx.x >> 4;          // 16 q-tiles of 128 rows
    const int tile0 = (blockIdx.x & 15) * 128;
    const int b     = bh >> 4;
    const int h     = bh & 15;

    const u16* qb = q + (size_t)bh * kN * kD;
    const u16* kb = k + (size_t)bh * kN * kD;
    const u16* vb = v + (size_t)bh * kN * kD;

    // Q B-fragments for 2 strips: lane holds Q[qrow][d = quad*8 + j]
    const int qrow0 = tile0 + w * 32 + l16;
    const int qrow1 = qrow0 + 16;
    v8bf qf[2][2];
    qf[0][0] = *(const v8bf*)(qb + (size_t)qrow0 * kD + quad * 8);
    qf[0][1] = *(const v8bf*)(qb + (size_t)qrow0 * kD + 32 + quad * 8);
    qf[1][0] = *(const v8bf*)(qb + (size_t)qrow1 * kD + quad * 8);
    qf[1][1] = *(const v8bf*)(qb + (size_t)qrow1 * kD + 32 + quad * 8);

    // staging geometry (constant per thread)
    // K: 2 rows x 32 dims per thread (4x 16B swizzled b128 writes)
    const int skr  = t >> 1;           // K row 0..127
    const int skh  = t & 1;            // K half (32 elems)
    // V: permuted 8 keys x 4 dims per thread -> 4x b128 transposed writes.
    const int vg   = t >> 4;           // frag chunk 0..15
    const int vdq  = t & 15;           // dim quad (dims vdq*4..+3)
    const int vrow0 = (vg >> 2) * 32 + (vg & 3) * 4;

    const u16* kp = kb + (size_t)skr * kD + skh * 32;
    const u16* vp = vb + (size_t)vrow0 * kD + vdq * 4;
    const uint4* mp0 = (const uint4*)(mbits + ((size_t)b * kN + qrow0) * 64);
    const uint4* mp1 = (const uint4*)(mbits + ((size_t)b * kN + qrow1) * 64);

    u16x8 kpre[4];
    u16x4 vpre[8];
    uint4 mpre0, mpre1;
    auto issue_prefetch = [&]() {
#pragma unroll
        for (int i = 0; i < 4; ++i)
            kpre[i] = *(const u16x8*)(kp + i * 8);
#pragma unroll
        for (int i = 0; i < 8; ++i)
            vpre[i] = *(const u16x4*)(vp + (i < 4 ? i * 64 : 1024 + (i - 4) * 64));
        mpre0 = *mp0; mpre1 = *mp1;
        kp += 128 * kD; vp += 128 * kD; ++mp0; ++mp1;
    };

    v8bf onesf;
#pragma unroll
    for (int j = 0; j < 8; ++j) onesf[j] = (__bf16)1.0f;

    v4f oacc[2][4];
    v4f rsacc[2];
#pragma unroll
    for (int qs = 0; qs < 2; ++qs) {
        rsacc[qs] = (v4f){0.f, 0.f, 0.f, 0.f};
#pragma unroll
        for (int i = 0; i < 4; ++i) oacc[qs][i] = (v4f){0.f, 0.f, 0.f, 0.f};
    }

    issue_prefetch();   // tile 0

    for (int kt = 0; kt < kN / 128; ++kt) {
        __syncthreads();   // prev tile's LDS reads done (WAR)

        // ---- stage tile kt from regs
        {
            const int cb = skh * 4;
            u16* drow = &Ks[skr * 64];
#pragma unroll
            for (int i = 0; i < 4; ++i)
                *(u16x8*)(&drow[((cb + i) ^ (skr & 7)) * 8]) = kpre[i];
        }
        {
#pragma unroll
            for (int dd = 0; dd < 4; ++dd) {
                const int d = vdq * 4 + dd;
                u16x8 col;
#pragma unroll
                for (int j = 0; j < 8; ++j) col[j] = vpre[j][dd];
                *(u16x8*)(&Vt[d * 128 + ((vg ^ (d & 15)) * 8)]) = col;
            }
        }
        const uint4 mc0 = mpre0, mc1 = mpre1;
        if (kt + 1 < kN / 128) issue_prefetch();   // regs free after ds_writes issue

        __syncthreads();   // staged tile visible

        const u32 mwa[2][4] = {{mc0.x, mc0.y, mc0.z, mc0.w},
                               {mc1.x, mc1.y, mc1.z, mc1.w}};
        v8bf pa[2][4];     // P A-fragments, built directly in registers

        // ---- S^T + softmax: lane gets s[reg] = S[key=nb*16+quad*4+reg][q=l16]
#pragma unroll
        for (int nb = 0; nb < 8; ++nb) {
            const int krow = nb * 16 + l16;
            const v8bf kf0 = *(const v8bf*)(&Ks[krow * 64 + ((quad       ^ (krow & 7)) * 8)]);
            const v8bf kf1 = *(const v8bf*)(&Ks[krow * 64 + (((quad + 4) ^ (krow & 7)) * 8)]);
#pragma unroll
            for (int qs = 0; qs < 2; ++qs) {
                v4f s = (v4f){0.f, 0.f, 0.f, 0.f};
                s = __builtin_amdgcn_mfma_f32_16x16x32_bf16(kf0, qf[qs][0], s, 0, 0, 0);
                s = __builtin_amdgcn_mfma_f32_16x16x32_bf16(kf1, qf[qs][1], s, 0, 0, 0);

                const u32 m4 = (mwa[qs][nb >> 1] >> ((nb & 1) * 16 + quad * 4)) & 0xFu;
                float e0 = fast_exp2(s[0]);
                float e1 = fast_exp2(s[1]);
                float e2 = fast_exp2(s[2]);
                float e3 = fast_exp2(s[3]);
                e0 = (m4 & 1u) ? 0.f : e0;
                e1 = (m4 & 2u) ? 0.f : e1;
                e2 = (m4 & 4u) ? 0.f : e2;
                e3 = (m4 & 8u) ? 0.f : e3;

                pa[qs][nb >> 1][(nb & 1) * 4 + 0] = (__bf16)e0;
                pa[qs][nb >> 1][(nb & 1) * 4 + 1] = (__bf16)e1;
                pa[qs][nb >> 1][(nb & 1) * 4 + 2] = (__bf16)e2;
                pa[qs][nb >> 1][(nb & 1) * 4 + 3] = (__bf16)e3;
            }
        }

        __builtin_amdgcn_s_setprio(1);
        // row-sums via ones-MFMA: rsacc row layout == oacc row layout
#pragma unroll
        for (int qs = 0; qs < 2; ++qs)
#pragma unroll
            for (int ks = 0; ks < 4; ++ks)
                rsacc[qs] = __builtin_amdgcn_mfma_f32_16x16x32_bf16(
                    pa[qs][ks], onesf, rsacc[qs], 0, 0, 0);
        // ---- PV: O[q][d] += P(32x128) @ V^T
#pragma unroll
        for (int ks = 0; ks < 4; ++ks)
#pragma unroll
            for (int db = 0; db < 4; ++db) {
                const int d = db * 16 + l16;
                const v8bf vf = *(const v8bf*)(&Vt[d * 128 + (((ks * 4 + quad) ^ (d & 15)) * 8)]);
#pragma unroll
                for (int qs = 0; qs < 2; ++qs)
                    oacc[qs][db] = __builtin_amdgcn_mfma_f32_16x16x32_bf16(
                        pa[qs][ks], vf, oacc[qs][db], 0, 0, 0);
            }
        __builtin_amdgcn_s_setprio(0);
    }

    // ---- normalize + store: rsacc rows already match oacc rows (quad*4+reg)
#pragma unroll
    for (int qs = 0; qs < 2; ++qs) {
        float inv[4];
#pragma unroll
        for (int reg = 0; reg < 4; ++reg) inv[reg] = 1.f / rsacc[qs][reg];
#pragma unroll
        for (int db = 0; db < 4; ++db)
#pragma unroll
            for (int reg = 0; reg < 4; ++reg) {
                const int row = tile0 + w * 32 + qs * 16 + quad * 4 + reg;
                const int col = h * 64 + db * 16 + l16;
                out[((size_t)(b * kN + row)) * kC + col] = f2bf(oacc[qs][db][reg] * inv[reg]);
            }
    }
}

// ------------------------------------------------------------------ launch
extern "C" void kernel_launch(void* const* d_in, const int* in_sizes, int n_in,
                              void* d_out, int out_size, void* d_ws, size_t ws_size,
                              hipStream_t stream)
{
    const float* x     = (const float*)d_in[0];
    const int*   mask  = (const int*)d_in[1];
    const float* Wqkv  = (const float*)d_in[2];
    const float* bqkv  = (const float*)d_in[3];
    const float* Wproj = (const float*)d_in[4];
    const float* bproj = (const float*)d_in[5];
    float* out = (float*)d_out;

    const size_t nx = (size_t)kB * kN * kC;
    const size_t qkv_elems = (size_t)kB * kH * kN * kD;
    u16* xb     = (u16*)d_ws;
    u16* qbuf   = xb + nx;
    u16* kbuf   = qbuf + qkv_elems;
    u16* vbuf   = kbuf + qkv_elems;
    u16* aob    = vbuf + qkv_elems;
    u16* Wqkvt  = aob + nx;
    u16* Wprojt = Wqkvt + (size_t)3 * kC * kC;
    u32* mbits  = (u32*)(Wprojt + (size_t)kC * kC);   // 2 MB bitmask

    // fused prep: cast + maskpack + both weight transposes, one dispatch
    prep_kernel<<<dim3(kPrepBlocks), dim3(256), 0, stream>>>(
        x, xb, mask, mbits, Wqkv, Wqkvt, Wproj, Wprojt);

    // 1-D grids (XCD swizzle inside): nwg = (N/128)*(M/128), % 8 == 0
    gemm_mfma_kernel<1><<<dim3((3 * kC / 128) * (kB * kN / 128)), dim3(256), 0, stream>>>(
        xb, Wqkvt, bqkv, nullptr, qbuf, kbuf, vbuf, kB * kN, 3 * kC, kC);

    attn_mfma_kernel<<<dim3(kB * kH * (kN / 128)), dim3(256), 0, stream>>>(
        qbuf, kbuf, vbuf, mbits, aob);

    gemm_mfma_kernel<0><<<dim3((kC / 128) * (kB * kN / 128)), dim3(256), 0, stream>>>(
        aob, Wprojt, bproj, out, nullptr, nullptr, nullptr, kB * kN, kC, kC);
}